// Round 1
// baseline (8823.866 us; speedup 1.0000x reference)
//
#include <hip/hip_runtime.h>
#include <hip/hip_bf16.h>

#define NN 100000
#define EE 1600000
#define GG 512
static constexpr float BN_EPS = 1e-5f;

// ---------------------------------------------------------------------------
// GEMM tiling: 64 rows x 128 cols per block, 256 threads, K-chunks of 16.
// Thread t: tc = t&31 owns cols [4*tc, 4*tc+4); tr = t>>5 owns rows [8*tr, 8*tr+8).
// ---------------------------------------------------------------------------

// p = h @ W   (A:[n,128], W:[128,128] row-major)
__global__ __launch_bounds__(256) void k_gemm1(
    const float* __restrict__ A, const float* __restrict__ W,
    float* __restrict__ P, int n)
{
    __shared__ float As[64][16];
    __shared__ float Ws[16][128];
    const int tid = threadIdx.x;
    const int tc = tid & 31, tr = tid >> 5;
    const int row0 = blockIdx.x * 64;
    const int lr = tid >> 2, lq = tid & 3;
    float acc[8][4] = {};
    for (int k0 = 0; k0 < 128; k0 += 16) {
        int gr = row0 + lr;
        float4 av = make_float4(0.f, 0.f, 0.f, 0.f);
        if (gr < n) av = *(const float4*)&A[(long long)gr * 128 + k0 + lq * 4];
        *(float4*)&As[lr][lq * 4] = av;
        #pragma unroll
        for (int s = 0; s < 2; ++s) {
            int idx = tid + s * 256;
            int r = idx >> 5, c = idx & 31;
            *(float4*)&Ws[r][c * 4] = *(const float4*)&W[(k0 + r) * 128 + c * 4];
        }
        __syncthreads();
        #pragma unroll
        for (int kk = 0; kk < 16; ++kk) {
            float4 w = *(const float4*)&Ws[kk][tc * 4];
            #pragma unroll
            for (int i = 0; i < 8; ++i) {
                float a = As[tr * 8 + i][kk];
                acc[i][0] = fmaf(a, w.x, acc[i][0]);
                acc[i][1] = fmaf(a, w.y, acc[i][1]);
                acc[i][2] = fmaf(a, w.z, acc[i][2]);
                acc[i][3] = fmaf(a, w.w, acc[i][3]);
            }
        }
        __syncthreads();
    }
    #pragma unroll
    for (int i = 0; i < 8; ++i) {
        int gr = row0 + tr * 8 + i;
        if (gr < n) {
            float4 v = make_float4(acc[i][0], acc[i][1], acc[i][2], acc[i][3]);
            *(float4*)&P[(long long)gr * 128 + tc * 4] = v;
        }
    }
}

// Layer 0: p = x @ W1[200:328] + W1[z] + W1[100+z]   (W1:[328,128])
__global__ __launch_bounds__(256) void k_embed(
    const float* __restrict__ X, const int* __restrict__ Z,
    const float* __restrict__ W1, float* __restrict__ P, int n)
{
    __shared__ float As[64][16];
    __shared__ float Ws[16][128];
    const int tid = threadIdx.x;
    const int tc = tid & 31, tr = tid >> 5;
    const int row0 = blockIdx.x * 64;
    const int lr = tid >> 2, lq = tid & 3;
    float acc[8][4] = {};
    for (int k0 = 0; k0 < 128; k0 += 16) {
        int gr = row0 + lr;
        float4 av = make_float4(0.f, 0.f, 0.f, 0.f);
        if (gr < n) av = *(const float4*)&X[(long long)gr * 128 + k0 + lq * 4];
        *(float4*)&As[lr][lq * 4] = av;
        #pragma unroll
        for (int s = 0; s < 2; ++s) {
            int idx = tid + s * 256;
            int r = idx >> 5, c = idx & 31;
            *(float4*)&Ws[r][c * 4] = *(const float4*)&W1[(200 + k0 + r) * 128 + c * 4];
        }
        __syncthreads();
        #pragma unroll
        for (int kk = 0; kk < 16; ++kk) {
            float4 w = *(const float4*)&Ws[kk][tc * 4];
            #pragma unroll
            for (int i = 0; i < 8; ++i) {
                float a = As[tr * 8 + i][kk];
                acc[i][0] = fmaf(a, w.x, acc[i][0]);
                acc[i][1] = fmaf(a, w.y, acc[i][1]);
                acc[i][2] = fmaf(a, w.z, acc[i][2]);
                acc[i][3] = fmaf(a, w.w, acc[i][3]);
            }
        }
        __syncthreads();
    }
    #pragma unroll
    for (int i = 0; i < 8; ++i) {
        int gr = row0 + tr * 8 + i;
        if (gr < n) {
            int zv = Z[gr];
            float4 w0 = *(const float4*)&W1[zv * 128 + tc * 4];
            float4 w1 = *(const float4*)&W1[(100 + zv) * 128 + tc * 4];
            float4 v = make_float4(acc[i][0] + w0.x + w1.x, acc[i][1] + w0.y + w1.y,
                                   acc[i][2] + w0.z + w1.z, acc[i][3] + w0.w + w1.w);
            *(float4*)&P[(long long)gr * 128 + tc * 4] = v;
        }
    }
}

// t[dst[e]] += p[src[e]]  (32 threads/edge, float4 gather, scalar atomics)
__global__ __launch_bounds__(256) void k_scatter(
    const float* __restrict__ P, float* __restrict__ T,
    const int* __restrict__ EI)
{
    int idx = blockIdx.x * 256 + threadIdx.x;
    int e = idx >> 5, q = idx & 31;
    if (e >= EE) return;
    int s = EI[e];
    int d = EI[EE + e];
    float4 v = *(const float4*)&P[(long long)s * 128 + q * 4];
    float* tp = &T[(long long)d * 128 + q * 4];
    atomicAdd(tp + 0, v.x);
    atomicAdd(tp + 1, v.y);
    atomicAdd(tp + 2, v.z);
    atomicAdd(tp + 3, v.w);
}

// v = relu( relu(p + t + b1) @ W2 + b2 ), in-place into P; fused colsum/colsumsq
__global__ __launch_bounds__(256) void k_gemm2(
    const float* __restrict__ T, float* __restrict__ P,
    const float* __restrict__ b1, const float* __restrict__ W2,
    const float* __restrict__ b2,
    float* __restrict__ colsum, float* __restrict__ colsq, int n)
{
    __shared__ float As[64][16];
    __shared__ float Ws[16][128];
    __shared__ float red[8][128];
    const int tid = threadIdx.x;
    const int tc = tid & 31, tr = tid >> 5;
    const int row0 = blockIdx.x * 64;
    const int lr = tid >> 2, lq = tid & 3;
    float acc[8][4] = {};
    for (int k0 = 0; k0 < 128; k0 += 16) {
        int gr = row0 + lr;
        float4 av = make_float4(0.f, 0.f, 0.f, 0.f);
        if (gr < n) {
            float4 pv = *(const float4*)&P[(long long)gr * 128 + k0 + lq * 4];
            float4 tv = *(const float4*)&T[(long long)gr * 128 + k0 + lq * 4];
            float4 bv = *(const float4*)&b1[k0 + lq * 4];
            av.x = fmaxf(pv.x + tv.x + bv.x, 0.f);
            av.y = fmaxf(pv.y + tv.y + bv.y, 0.f);
            av.z = fmaxf(pv.z + tv.z + bv.z, 0.f);
            av.w = fmaxf(pv.w + tv.w + bv.w, 0.f);
        }
        *(float4*)&As[lr][lq * 4] = av;
        #pragma unroll
        for (int s = 0; s < 2; ++s) {
            int idx = tid + s * 256;
            int r = idx >> 5, c = idx & 31;
            *(float4*)&Ws[r][c * 4] = *(const float4*)&W2[(k0 + r) * 128 + c * 4];
        }
        __syncthreads();
        #pragma unroll
        for (int kk = 0; kk < 16; ++kk) {
            float4 w = *(const float4*)&Ws[kk][tc * 4];
            #pragma unroll
            for (int i = 0; i < 8; ++i) {
                float a = As[tr * 8 + i][kk];
                acc[i][0] = fmaf(a, w.x, acc[i][0]);
                acc[i][1] = fmaf(a, w.y, acc[i][1]);
                acc[i][2] = fmaf(a, w.z, acc[i][2]);
                acc[i][3] = fmaf(a, w.w, acc[i][3]);
            }
        }
        __syncthreads();
    }
    float4 b2v = *(const float4*)&b2[tc * 4];
    float s_[4] = {0.f, 0.f, 0.f, 0.f};
    float q_[4] = {0.f, 0.f, 0.f, 0.f};
    #pragma unroll
    for (int i = 0; i < 8; ++i) {
        int gr = row0 + tr * 8 + i;
        if (gr < n) {
            float4 v;
            v.x = fmaxf(acc[i][0] + b2v.x, 0.f);
            v.y = fmaxf(acc[i][1] + b2v.y, 0.f);
            v.z = fmaxf(acc[i][2] + b2v.z, 0.f);
            v.w = fmaxf(acc[i][3] + b2v.w, 0.f);
            *(float4*)&P[(long long)gr * 128 + tc * 4] = v;
            s_[0] += v.x; s_[1] += v.y; s_[2] += v.z; s_[3] += v.w;
            q_[0] += v.x * v.x; q_[1] += v.y * v.y; q_[2] += v.z * v.z; q_[3] += v.w * v.w;
        }
    }
    __syncthreads();
    #pragma unroll
    for (int j = 0; j < 4; ++j) red[tr][tc * 4 + j] = s_[j];
    __syncthreads();
    if (tid < 128) {
        float t = 0.f;
        #pragma unroll
        for (int r = 0; r < 8; ++r) t += red[r][tid];
        atomicAdd(&colsum[tid], t);
    }
    __syncthreads();
    #pragma unroll
    for (int j = 0; j < 4; ++j) red[tr][tc * 4 + j] = q_[j];
    __syncthreads();
    if (tid < 128) {
        float t = 0.f;
        #pragma unroll
        for (int r = 0; r < 8; ++r) t += red[r][tid];
        atomicAdd(&colsq[tid], t);
    }
}

__global__ void k_bnfin(const float* __restrict__ colsum, const float* __restrict__ colsq,
                        const float* __restrict__ g, const float* __restrict__ be,
                        float* __restrict__ scale, float* __restrict__ shift)
{
    int c = threadIdx.x;
    float inv_n = 1.0f / (float)NN;
    float mu = colsum[c] * inv_n;
    float var = colsq[c] * inv_n - mu * mu;
    float sc = g[c] * rsqrtf(var + BN_EPS);
    scale[c] = sc;
    shift[c] = be[c] - mu * sc;
}

__global__ __launch_bounds__(256) void k_bnapply(
    const float* __restrict__ V, const float* __restrict__ scale,
    const float* __restrict__ shift, float* __restrict__ H)
{
    int idx = blockIdx.x * 256 + threadIdx.x;  // float4 index
    if (idx >= NN * 32) return;
    int c4 = (idx & 31) * 4;
    float4 v = *(const float4*)&V[(long long)idx * 4];
    float4 sc = *(const float4*)&scale[c4];
    float4 sh = *(const float4*)&shift[c4];
    v.x = fmaf(v.x, sc.x, sh.x);
    v.y = fmaf(v.y, sc.y, sh.y);
    v.z = fmaf(v.z, sc.z, sh.z);
    v.w = fmaf(v.w, sc.w, sh.w);
    *(float4*)&H[(long long)idx * 4] = v;
}

// mean-pool per graph (batch sorted): block = graph, thread = column
__global__ __launch_bounds__(128) void k_pool(
    const float* __restrict__ H, const int* __restrict__ batch,
    float* __restrict__ pooled, int loff)
{
    int g = blockIdx.x;
    int c = threadIdx.x;
    int lo = 0, hi = NN;
    while (lo < hi) { int mid = (lo + hi) >> 1; if (batch[mid] < g) lo = mid + 1; else hi = mid; }
    int s = lo;
    lo = s; hi = NN;
    while (lo < hi) { int mid = (lo + hi) >> 1; if (batch[mid] < g + 1) lo = mid + 1; else hi = mid; }
    int e = lo;
    float acc = 0.f;
    for (int i = s; i < e; ++i) acc += H[(long long)i * 128 + c];
    int cnt = e - s;
    pooled[g * 384 + loff + c] = acc / (float)(cnt > 0 ? cnt : 1);
}

// out[g] = relu(pooled[g] @ Wl1 + bl1) @ Wl2 + bl2
__global__ __launch_bounds__(128) void k_final(
    const float* __restrict__ pooled,
    const float* __restrict__ Wl1, const float* __restrict__ bl1,
    const float* __restrict__ Wl2, const float* __restrict__ bl2,
    float* __restrict__ out)
{
    __shared__ float pr[384];
    __shared__ float red[128];
    int g = blockIdx.x, j = threadIdx.x;
    for (int i = j; i < 384; i += 128) pr[i] = pooled[g * 384 + i];
    __syncthreads();
    float acc = bl1[j];
    for (int k = 0; k < 384; ++k) acc = fmaf(pr[k], Wl1[k * 128 + j], acc);
    float r = fmaxf(acc, 0.f) * Wl2[j];
    red[j] = r;
    __syncthreads();
    for (int off = 64; off > 0; off >>= 1) {
        if (j < off) red[j] += red[j + off];
        __syncthreads();
    }
    if (j == 0) out[g] = red[0] + bl2[0];
}

extern "C" void kernel_launch(void* const* d_in, const int* in_sizes, int n_in,
                              void* d_out, int out_size, void* d_ws, size_t ws_size,
                              hipStream_t stream)
{
    const float* x     = (const float*)d_in[0];
    const int*   z     = (const int*)d_in[1];
    const int*   ei    = (const int*)d_in[2];
    const int*   batch = (const int*)d_in[3];
    const float* W1a[3] = {(const float*)d_in[4],  (const float*)d_in[10], (const float*)d_in[16]};
    const float* b1a[3] = {(const float*)d_in[5],  (const float*)d_in[11], (const float*)d_in[17]};
    const float* W2a[3] = {(const float*)d_in[6],  (const float*)d_in[12], (const float*)d_in[18]};
    const float* b2a[3] = {(const float*)d_in[7],  (const float*)d_in[13], (const float*)d_in[19]};
    const float* ga[3]  = {(const float*)d_in[8],  (const float*)d_in[14], (const float*)d_in[20]};
    const float* bea[3] = {(const float*)d_in[9],  (const float*)d_in[15], (const float*)d_in[21]};
    const float* Wl1 = (const float*)d_in[22];
    const float* bl1 = (const float*)d_in[23];
    const float* Wl2 = (const float*)d_in[24];
    const float* bl2 = (const float*)d_in[25];
    float* out = (float*)d_out;

    char* ws = (char*)d_ws;
    size_t off = 0;
    auto alloc = [&](size_t bytes) {
        void* p = ws + off;
        off += (bytes + 255) & ~(size_t)255;
        return p;
    };
    float* P      = (float*)alloc((size_t)NN * 128 * 4);
    float* T      = (float*)alloc((size_t)NN * 128 * 4);
    float* H      = (float*)alloc((size_t)NN * 128 * 4);
    float* colsum = (float*)alloc(128 * 4);
    float* colsq  = (float*)alloc(128 * 4);
    float* scale  = (float*)alloc(128 * 4);
    float* shift  = (float*)alloc(128 * 4);
    float* pooled = (float*)alloc((size_t)GG * 384 * 4);

    const int gemmBlocks = (NN + 63) / 64;
    const int scatBlocks = (EE * 32 + 255) / 256;
    const int bnBlocks   = (NN * 32 + 255) / 256;

    for (int l = 0; l < 3; ++l) {
        hipMemsetAsync(T, 0, (size_t)NN * 128 * 4, stream);
        hipMemsetAsync(colsum, 0, 128 * 4, stream);
        hipMemsetAsync(colsq, 0, 128 * 4, stream);
        if (l == 0)
            k_embed<<<gemmBlocks, 256, 0, stream>>>(x, z, W1a[0], P, NN);
        else
            k_gemm1<<<gemmBlocks, 256, 0, stream>>>(H, W1a[l], P, NN);
        k_scatter<<<scatBlocks, 256, 0, stream>>>(P, T, ei);
        k_gemm2<<<gemmBlocks, 256, 0, stream>>>(T, P, b1a[l], W2a[l], b2a[l], colsum, colsq, NN);
        k_bnfin<<<1, 128, 0, stream>>>(colsum, colsq, ga[l], bea[l], scale, shift);
        k_bnapply<<<bnBlocks, 256, 0, stream>>>(P, scale, shift, H);
        k_pool<<<GG, 128, 0, stream>>>(H, batch, pooled, l * 128);
    }
    k_final<<<GG, 128, 0, stream>>>(pooled, Wl1, bl1, Wl2, bl2, out);
}

// Round 2
// 1495.348 us; speedup vs baseline: 5.9009x; 5.9009x over previous
//
#include <hip/hip_runtime.h>
#include <hip/hip_bf16.h>

#define NN 100000
#define EE 1600000
#define GG 512
static constexpr float BN_EPS = 1e-5f;

// ---------------------------------------------------------------------------
// CSR build: histogram by dst -> exclusive scan -> cursor fill
// ---------------------------------------------------------------------------

__global__ __launch_bounds__(256) void k_hist(const int* __restrict__ EI, int* __restrict__ hist)
{
    int e = blockIdx.x * 256 + threadIdx.x;
    if (e < EE) atomicAdd(&hist[EI[EE + e]], 1);
}

// single-block exclusive scan over NN counts -> row_start[NN+1], cursor copy
__global__ __launch_bounds__(1024) void k_scan(const int* __restrict__ hist,
                                               int* __restrict__ row_start,
                                               int* __restrict__ cursor)
{
    __shared__ int sums[1024];
    const int t = threadIdx.x;
    const int per = (NN + 1023) / 1024;
    const int base = t * per;
    const int lim = base + per < NN ? base + per : NN;
    int s = 0;
    for (int i = base; i < lim; ++i) s += hist[i];
    sums[t] = s;
    __syncthreads();
    for (int off = 1; off < 1024; off <<= 1) {
        int v = (t >= off) ? sums[t - off] : 0;
        __syncthreads();
        sums[t] += v;
        __syncthreads();
    }
    int run = sums[t] - s;  // exclusive prefix
    for (int i = base; i < lim; ++i) {
        int c = hist[i];
        row_start[i] = run;
        cursor[i] = run;
        run += c;
    }
    if (t == 0) row_start[NN] = EE;
}

__global__ __launch_bounds__(256) void k_fill(const int* __restrict__ EI,
                                              int* __restrict__ cursor,
                                              int* __restrict__ ssrc)
{
    int e = blockIdx.x * 256 + threadIdx.x;
    if (e < EE) {
        int d = EI[EE + e];
        int pos = atomicAdd(&cursor[d], 1);
        ssrc[pos] = EI[e];
    }
}

// ---------------------------------------------------------------------------
// GEMM tiling: 64 rows x 128 cols per block, 256 threads, K-chunks of 16.
// ---------------------------------------------------------------------------

// p = h @ W   (A:[n,128], W:[128,128] row-major)
__global__ __launch_bounds__(256) void k_gemm1(
    const float* __restrict__ A, const float* __restrict__ W,
    float* __restrict__ P, int n)
{
    __shared__ float As[64][16];
    __shared__ float Ws[16][128];
    const int tid = threadIdx.x;
    const int tc = tid & 31, tr = tid >> 5;
    const int row0 = blockIdx.x * 64;
    const int lr = tid >> 2, lq = tid & 3;
    float acc[8][4] = {};
    for (int k0 = 0; k0 < 128; k0 += 16) {
        int gr = row0 + lr;
        float4 av = make_float4(0.f, 0.f, 0.f, 0.f);
        if (gr < n) av = *(const float4*)&A[(long long)gr * 128 + k0 + lq * 4];
        *(float4*)&As[lr][lq * 4] = av;
        #pragma unroll
        for (int s = 0; s < 2; ++s) {
            int idx = tid + s * 256;
            int r = idx >> 5, c = idx & 31;
            *(float4*)&Ws[r][c * 4] = *(const float4*)&W[(k0 + r) * 128 + c * 4];
        }
        __syncthreads();
        #pragma unroll
        for (int kk = 0; kk < 16; ++kk) {
            float4 w = *(const float4*)&Ws[kk][tc * 4];
            #pragma unroll
            for (int i = 0; i < 8; ++i) {
                float a = As[tr * 8 + i][kk];
                acc[i][0] = fmaf(a, w.x, acc[i][0]);
                acc[i][1] = fmaf(a, w.y, acc[i][1]);
                acc[i][2] = fmaf(a, w.z, acc[i][2]);
                acc[i][3] = fmaf(a, w.w, acc[i][3]);
            }
        }
        __syncthreads();
    }
    #pragma unroll
    for (int i = 0; i < 8; ++i) {
        int gr = row0 + tr * 8 + i;
        if (gr < n) {
            float4 v = make_float4(acc[i][0], acc[i][1], acc[i][2], acc[i][3]);
            *(float4*)&P[(long long)gr * 128 + tc * 4] = v;
        }
    }
}

// Layer 0: p = x @ W1[200:328] + W1[z] + W1[100+z]   (W1:[328,128])
__global__ __launch_bounds__(256) void k_embed(
    const float* __restrict__ X, const int* __restrict__ Z,
    const float* __restrict__ W1, float* __restrict__ P, int n)
{
    __shared__ float As[64][16];
    __shared__ float Ws[16][128];
    const int tid = threadIdx.x;
    const int tc = tid & 31, tr = tid >> 5;
    const int row0 = blockIdx.x * 64;
    const int lr = tid >> 2, lq = tid & 3;
    float acc[8][4] = {};
    for (int k0 = 0; k0 < 128; k0 += 16) {
        int gr = row0 + lr;
        float4 av = make_float4(0.f, 0.f, 0.f, 0.f);
        if (gr < n) av = *(const float4*)&X[(long long)gr * 128 + k0 + lq * 4];
        *(float4*)&As[lr][lq * 4] = av;
        #pragma unroll
        for (int s = 0; s < 2; ++s) {
            int idx = tid + s * 256;
            int r = idx >> 5, c = idx & 31;
            *(float4*)&Ws[r][c * 4] = *(const float4*)&W1[(200 + k0 + r) * 128 + c * 4];
        }
        __syncthreads();
        #pragma unroll
        for (int kk = 0; kk < 16; ++kk) {
            float4 w = *(const float4*)&Ws[kk][tc * 4];
            #pragma unroll
            for (int i = 0; i < 8; ++i) {
                float a = As[tr * 8 + i][kk];
                acc[i][0] = fmaf(a, w.x, acc[i][0]);
                acc[i][1] = fmaf(a, w.y, acc[i][1]);
                acc[i][2] = fmaf(a, w.z, acc[i][2]);
                acc[i][3] = fmaf(a, w.w, acc[i][3]);
            }
        }
        __syncthreads();
    }
    #pragma unroll
    for (int i = 0; i < 8; ++i) {
        int gr = row0 + tr * 8 + i;
        if (gr < n) {
            int zv = Z[gr];
            float4 w0 = *(const float4*)&W1[zv * 128 + tc * 4];
            float4 w1 = *(const float4*)&W1[(100 + zv) * 128 + tc * 4];
            float4 v = make_float4(acc[i][0] + w0.x + w1.x, acc[i][1] + w0.y + w1.y,
                                   acc[i][2] + w0.z + w1.z, acc[i][3] + w0.w + w1.w);
            *(float4*)&P[(long long)gr * 128 + tc * 4] = v;
        }
    }
}

// M[i] = relu( P[i] + sum_{j in N(i)} P[j] + b1 )   — CSR gather, no atomics.
// 32-lane team per node, lane q owns cols [4q,4q+4).
__global__ __launch_bounds__(256) void k_aggregate(
    const float* __restrict__ P, const int* __restrict__ row_start,
    const int* __restrict__ ssrc, const float* __restrict__ b1,
    float* __restrict__ M)
{
    int idx = blockIdx.x * 256 + threadIdx.x;
    int node = idx >> 5, q = idx & 31;
    if (node >= NN) return;
    int s0 = row_start[node], s1 = row_start[node + 1];
    float4 bv = *(const float4*)&b1[q * 4];
    float4 pv = *(const float4*)&P[(long long)node * 128 + q * 4];
    float ax = pv.x + bv.x, ay = pv.y + bv.y, az = pv.z + bv.z, aw = pv.w + bv.w;
    int e = s0;
    for (; e + 1 < s1; e += 2) {
        int sa = ssrc[e], sb = ssrc[e + 1];
        float4 va = *(const float4*)&P[(long long)sa * 128 + q * 4];
        float4 vb = *(const float4*)&P[(long long)sb * 128 + q * 4];
        ax += va.x + vb.x; ay += va.y + vb.y;
        az += va.z + vb.z; aw += va.w + vb.w;
    }
    if (e < s1) {
        int sa = ssrc[e];
        float4 va = *(const float4*)&P[(long long)sa * 128 + q * 4];
        ax += va.x; ay += va.y; az += va.z; aw += va.w;
    }
    float4 o = make_float4(fmaxf(ax, 0.f), fmaxf(ay, 0.f), fmaxf(az, 0.f), fmaxf(aw, 0.f));
    *(float4*)&M[(long long)node * 128 + q * 4] = o;
}

// v = relu( M @ W2 + b2 ) into P; fused colsum/colsumsq for BN stats
__global__ __launch_bounds__(256) void k_gemm2(
    const float* __restrict__ M, float* __restrict__ P,
    const float* __restrict__ W2, const float* __restrict__ b2,
    float* __restrict__ colsum, float* __restrict__ colsq, int n)
{
    __shared__ float As[64][16];
    __shared__ float Ws[16][128];
    __shared__ float red[8][128];
    const int tid = threadIdx.x;
    const int tc = tid & 31, tr = tid >> 5;
    const int row0 = blockIdx.x * 64;
    const int lr = tid >> 2, lq = tid & 3;
    float acc[8][4] = {};
    for (int k0 = 0; k0 < 128; k0 += 16) {
        int gr = row0 + lr;
        float4 av = make_float4(0.f, 0.f, 0.f, 0.f);
        if (gr < n) av = *(const float4*)&M[(long long)gr * 128 + k0 + lq * 4];
        *(float4*)&As[lr][lq * 4] = av;
        #pragma unroll
        for (int s = 0; s < 2; ++s) {
            int idx = tid + s * 256;
            int r = idx >> 5, c = idx & 31;
            *(float4*)&Ws[r][c * 4] = *(const float4*)&W2[(k0 + r) * 128 + c * 4];
        }
        __syncthreads();
        #pragma unroll
        for (int kk = 0; kk < 16; ++kk) {
            float4 w = *(const float4*)&Ws[kk][tc * 4];
            #pragma unroll
            for (int i = 0; i < 8; ++i) {
                float a = As[tr * 8 + i][kk];
                acc[i][0] = fmaf(a, w.x, acc[i][0]);
                acc[i][1] = fmaf(a, w.y, acc[i][1]);
                acc[i][2] = fmaf(a, w.z, acc[i][2]);
                acc[i][3] = fmaf(a, w.w, acc[i][3]);
            }
        }
        __syncthreads();
    }
    float4 b2v = *(const float4*)&b2[tc * 4];
    float s_[4] = {0.f, 0.f, 0.f, 0.f};
    float q_[4] = {0.f, 0.f, 0.f, 0.f};
    #pragma unroll
    for (int i = 0; i < 8; ++i) {
        int gr = row0 + tr * 8 + i;
        if (gr < n) {
            float4 v;
            v.x = fmaxf(acc[i][0] + b2v.x, 0.f);
            v.y = fmaxf(acc[i][1] + b2v.y, 0.f);
            v.z = fmaxf(acc[i][2] + b2v.z, 0.f);
            v.w = fmaxf(acc[i][3] + b2v.w, 0.f);
            *(float4*)&P[(long long)gr * 128 + tc * 4] = v;
            s_[0] += v.x; s_[1] += v.y; s_[2] += v.z; s_[3] += v.w;
            q_[0] += v.x * v.x; q_[1] += v.y * v.y; q_[2] += v.z * v.z; q_[3] += v.w * v.w;
        }
    }
    __syncthreads();
    #pragma unroll
    for (int j = 0; j < 4; ++j) red[tr][tc * 4 + j] = s_[j];
    __syncthreads();
    if (tid < 128) {
        float t = 0.f;
        #pragma unroll
        for (int r = 0; r < 8; ++r) t += red[r][tid];
        atomicAdd(&colsum[tid], t);
    }
    __syncthreads();
    #pragma unroll
    for (int j = 0; j < 4; ++j) red[tr][tc * 4 + j] = q_[j];
    __syncthreads();
    if (tid < 128) {
        float t = 0.f;
        #pragma unroll
        for (int r = 0; r < 8; ++r) t += red[r][tid];
        atomicAdd(&colsq[tid], t);
    }
}

__global__ void k_bnfin(const float* __restrict__ colsum, const float* __restrict__ colsq,
                        const float* __restrict__ g, const float* __restrict__ be,
                        float* __restrict__ scale, float* __restrict__ shift)
{
    int c = threadIdx.x;
    float inv_n = 1.0f / (float)NN;
    float mu = colsum[c] * inv_n;
    float var = colsq[c] * inv_n - mu * mu;
    float sc = g[c] * rsqrtf(var + BN_EPS);
    scale[c] = sc;
    shift[c] = be[c] - mu * sc;
}

__global__ __launch_bounds__(256) void k_bnapply(
    const float* __restrict__ V, const float* __restrict__ scale,
    const float* __restrict__ shift, float* __restrict__ H)
{
    int idx = blockIdx.x * 256 + threadIdx.x;  // float4 index
    if (idx >= NN * 32) return;
    int c4 = (idx & 31) * 4;
    float4 v = *(const float4*)&V[(long long)idx * 4];
    float4 sc = *(const float4*)&scale[c4];
    float4 sh = *(const float4*)&shift[c4];
    v.x = fmaf(v.x, sc.x, sh.x);
    v.y = fmaf(v.y, sc.y, sh.y);
    v.z = fmaf(v.z, sc.z, sh.z);
    v.w = fmaf(v.w, sc.w, sh.w);
    *(float4*)&H[(long long)idx * 4] = v;
}

// mean-pool per graph (batch sorted): block = graph, thread = column
__global__ __launch_bounds__(128) void k_pool(
    const float* __restrict__ H, const int* __restrict__ batch,
    float* __restrict__ pooled, int loff)
{
    int g = blockIdx.x;
    int c = threadIdx.x;
    int lo = 0, hi = NN;
    while (lo < hi) { int mid = (lo + hi) >> 1; if (batch[mid] < g) lo = mid + 1; else hi = mid; }
    int s = lo;
    lo = s; hi = NN;
    while (lo < hi) { int mid = (lo + hi) >> 1; if (batch[mid] < g + 1) lo = mid + 1; else hi = mid; }
    int e = lo;
    float acc = 0.f;
    for (int i = s; i < e; ++i) acc += H[(long long)i * 128 + c];
    int cnt = e - s;
    pooled[g * 384 + loff + c] = acc / (float)(cnt > 0 ? cnt : 1);
}

// out[g] = relu(pooled[g] @ Wl1 + bl1) @ Wl2 + bl2
__global__ __launch_bounds__(128) void k_final(
    const float* __restrict__ pooled,
    const float* __restrict__ Wl1, const float* __restrict__ bl1,
    const float* __restrict__ Wl2, const float* __restrict__ bl2,
    float* __restrict__ out)
{
    __shared__ float pr[384];
    __shared__ float red[128];
    int g = blockIdx.x, j = threadIdx.x;
    for (int i = j; i < 384; i += 128) pr[i] = pooled[g * 384 + i];
    __syncthreads();
    float acc = bl1[j];
    for (int k = 0; k < 384; ++k) acc = fmaf(pr[k], Wl1[k * 128 + j], acc);
    float r = fmaxf(acc, 0.f) * Wl2[j];
    red[j] = r;
    __syncthreads();
    for (int off = 64; off > 0; off >>= 1) {
        if (j < off) red[j] += red[j + off];
        __syncthreads();
    }
    if (j == 0) out[g] = red[0] + bl2[0];
}

extern "C" void kernel_launch(void* const* d_in, const int* in_sizes, int n_in,
                              void* d_out, int out_size, void* d_ws, size_t ws_size,
                              hipStream_t stream)
{
    const float* x     = (const float*)d_in[0];
    const int*   z     = (const int*)d_in[1];
    const int*   ei    = (const int*)d_in[2];
    const int*   batch = (const int*)d_in[3];
    const float* W1a[3] = {(const float*)d_in[4],  (const float*)d_in[10], (const float*)d_in[16]};
    const float* b1a[3] = {(const float*)d_in[5],  (const float*)d_in[11], (const float*)d_in[17]};
    const float* W2a[3] = {(const float*)d_in[6],  (const float*)d_in[12], (const float*)d_in[18]};
    const float* b2a[3] = {(const float*)d_in[7],  (const float*)d_in[13], (const float*)d_in[19]};
    const float* ga[3]  = {(const float*)d_in[8],  (const float*)d_in[14], (const float*)d_in[20]};
    const float* bea[3] = {(const float*)d_in[9],  (const float*)d_in[15], (const float*)d_in[21]};
    const float* Wl1 = (const float*)d_in[22];
    const float* bl1 = (const float*)d_in[23];
    const float* Wl2 = (const float*)d_in[24];
    const float* bl2 = (const float*)d_in[25];
    float* out = (float*)d_out;

    char* ws = (char*)d_ws;
    size_t off = 0;
    auto alloc = [&](size_t bytes) {
        void* p = ws + off;
        off += (bytes + 255) & ~(size_t)255;
        return p;
    };
    float* P       = (float*)alloc((size_t)NN * 128 * 4);
    float* M       = (float*)alloc((size_t)NN * 128 * 4);
    float* H       = (float*)alloc((size_t)NN * 128 * 4);
    int*   hist    = (int*)alloc((size_t)NN * 4);
    int*   row_st  = (int*)alloc((size_t)(NN + 1) * 4);
    int*   cursor  = (int*)alloc((size_t)NN * 4);
    int*   ssrc    = (int*)alloc((size_t)EE * 4);
    float* colsum  = (float*)alloc(128 * 4);
    float* colsq   = (float*)alloc(128 * 4);
    float* scale   = (float*)alloc(128 * 4);
    float* shift   = (float*)alloc(128 * 4);
    float* pooled  = (float*)alloc((size_t)GG * 384 * 4);

    const int gemmBlocks = (NN + 63) / 64;
    const int edgeBlocks = (EE + 255) / 256;
    const int aggBlocks  = (NN * 32 + 255) / 256;
    const int bnBlocks   = (NN * 32 + 255) / 256;

    // ---- CSR build (once per call; reused for all 3 layers) ----
    hipMemsetAsync(hist, 0, (size_t)NN * 4, stream);
    k_hist<<<edgeBlocks, 256, 0, stream>>>(ei, hist);
    k_scan<<<1, 1024, 0, stream>>>(hist, row_st, cursor);
    k_fill<<<edgeBlocks, 256, 0, stream>>>(ei, cursor, ssrc);

    for (int l = 0; l < 3; ++l) {
        hipMemsetAsync(colsum, 0, 128 * 4, stream);
        hipMemsetAsync(colsq, 0, 128 * 4, stream);
        if (l == 0)
            k_embed<<<gemmBlocks, 256, 0, stream>>>(x, z, W1a[0], P, NN);
        else
            k_gemm1<<<gemmBlocks, 256, 0, stream>>>(H, W1a[l], P, NN);
        k_aggregate<<<aggBlocks, 256, 0, stream>>>(P, row_st, ssrc, b1a[l], M);
        k_gemm2<<<gemmBlocks, 256, 0, stream>>>(M, P, W2a[l], b2a[l], colsum, colsq, NN);
        k_bnfin<<<1, 128, 0, stream>>>(colsum, colsq, ga[l], bea[l], scale, shift);
        k_bnapply<<<bnBlocks, 256, 0, stream>>>(P, scale, shift, H);
        k_pool<<<GG, 128, 0, stream>>>(H, batch, pooled, l * 128);
    }
    k_final<<<GG, 128, 0, stream>>>(pooled, Wl1, bl1, Wl2, bl2, out);
}

// Round 3
// 1261.644 us; speedup vs baseline: 6.9939x; 1.1852x over previous
//
#include <hip/hip_runtime.h>
#include <hip/hip_bf16.h>

#define NN 100000
#define EE 1600000
#define GG 512
#define SCAN_CHUNK 512
#define SCAN_BLOCKS ((NN + SCAN_CHUNK - 1) / SCAN_CHUNK)   // 196
static constexpr float BN_EPS = 1e-5f;

// ---------------------------------------------------------------------------
// CSR build: histogram -> 3-phase parallel exclusive scan -> cursor fill
// ---------------------------------------------------------------------------

__global__ __launch_bounds__(256) void k_hist(const int* __restrict__ EI, int* __restrict__ hist)
{
    int e = blockIdx.x * 256 + threadIdx.x;
    if (e < EE) atomicAdd(&hist[EI[EE + e]], 1);
}

// phase 1: per-chunk (512 counts) partial sums
__global__ __launch_bounds__(256) void k_scan1(const int* __restrict__ hist,
                                               int* __restrict__ partials)
{
    __shared__ int red[256];
    int b = blockIdx.x, t = threadIdx.x;
    int i0 = b * SCAN_CHUNK + 2 * t;
    int e0 = (i0 < NN) ? hist[i0] : 0;
    int e1 = (i0 + 1 < NN) ? hist[i0 + 1] : 0;
    red[t] = e0 + e1;
    __syncthreads();
    for (int off = 128; off > 0; off >>= 1) {
        if (t < off) red[t] += red[t + off];
        __syncthreads();
    }
    if (t == 0) partials[b] = red[0];
}

// phase 2: exclusive scan of the 196 partials (single tiny block)
__global__ __launch_bounds__(256) void k_scan2(const int* __restrict__ partials,
                                               int* __restrict__ poffs,
                                               int* __restrict__ row_start)
{
    __shared__ int s[256];
    int t = threadIdx.x;
    int v = (t < SCAN_BLOCKS) ? partials[t] : 0;
    s[t] = v;
    __syncthreads();
    for (int off = 1; off < 256; off <<= 1) {
        int u = (t >= off) ? s[t - off] : 0;
        __syncthreads();
        s[t] += u;
        __syncthreads();
    }
    if (t < SCAN_BLOCKS) poffs[t] = s[t] - v;
    if (t == 0) row_start[NN] = EE;
}

// phase 3: per-chunk exclusive scan with global offset -> row_start + cursor
__global__ __launch_bounds__(256) void k_scan3(const int* __restrict__ hist,
                                               const int* __restrict__ poffs,
                                               int* __restrict__ row_start,
                                               int* __restrict__ cursor)
{
    __shared__ int s[256];
    int b = blockIdx.x, t = threadIdx.x;
    int i0 = b * SCAN_CHUNK + 2 * t;
    int e0 = (i0 < NN) ? hist[i0] : 0;
    int e1 = (i0 + 1 < NN) ? hist[i0 + 1] : 0;
    int pair = e0 + e1;
    s[t] = pair;
    __syncthreads();
    for (int off = 1; off < 256; off <<= 1) {
        int u = (t >= off) ? s[t - off] : 0;
        __syncthreads();
        s[t] += u;
        __syncthreads();
    }
    int base = poffs[b] + s[t] - pair;
    if (i0 < NN)     { row_start[i0] = base;       cursor[i0] = base; }
    if (i0 + 1 < NN) { row_start[i0 + 1] = base + e0; cursor[i0 + 1] = base + e0; }
}

__global__ __launch_bounds__(256) void k_fill(const int* __restrict__ EI,
                                              int* __restrict__ cursor,
                                              int* __restrict__ ssrc)
{
    int e = blockIdx.x * 256 + threadIdx.x;
    if (e < EE) {
        int d = EI[EE + e];
        int pos = atomicAdd(&cursor[d], 1);
        ssrc[pos] = EI[e];
    }
}

// ---------------------------------------------------------------------------
// BN folding: W1f[k][j] = scale[k]*W1[k][j];  cvec[j] = sum_k shift[k]*W1[k][j]
// ---------------------------------------------------------------------------

__global__ __launch_bounds__(256) void k_foldW(const float* __restrict__ W1,
                                               const float* __restrict__ scale,
                                               float* __restrict__ W1f)
{
    int idx = blockIdx.x * 256 + threadIdx.x;   // 16384 elements
    int k = idx >> 7;
    W1f[idx] = scale[k] * W1[idx];
}

__global__ __launch_bounds__(128) void k_cvec(const float* __restrict__ W1,
                                              const float* __restrict__ shift,
                                              float* __restrict__ cvec)
{
    int j = threadIdx.x;
    float acc = 0.f;
    for (int k = 0; k < 128; ++k) acc = fmaf(shift[k], W1[k * 128 + j], acc);
    cvec[j] = acc;
}

// ---------------------------------------------------------------------------
// GEMM tiling: 64 rows x 128 cols per block, 256 threads, K-chunks of 16.
// ---------------------------------------------------------------------------

// P = A @ W   (A:[n,128], W:[128,128] row-major)
__global__ __launch_bounds__(256) void k_gemm1(
    const float* __restrict__ A, const float* __restrict__ W,
    float* __restrict__ P, int n)
{
    __shared__ float As[64][16];
    __shared__ float Ws[16][128];
    const int tid = threadIdx.x;
    const int tc = tid & 31, tr = tid >> 5;
    const int row0 = blockIdx.x * 64;
    const int lr = tid >> 2, lq = tid & 3;
    float acc[8][4] = {};
    for (int k0 = 0; k0 < 128; k0 += 16) {
        int gr = row0 + lr;
        float4 av = make_float4(0.f, 0.f, 0.f, 0.f);
        if (gr < n) av = *(const float4*)&A[(long long)gr * 128 + k0 + lq * 4];
        *(float4*)&As[lr][lq * 4] = av;
        #pragma unroll
        for (int s = 0; s < 2; ++s) {
            int idx = tid + s * 256;
            int r = idx >> 5, c = idx & 31;
            *(float4*)&Ws[r][c * 4] = *(const float4*)&W[(k0 + r) * 128 + c * 4];
        }
        __syncthreads();
        #pragma unroll
        for (int kk = 0; kk < 16; ++kk) {
            float4 w = *(const float4*)&Ws[kk][tc * 4];
            #pragma unroll
            for (int i = 0; i < 8; ++i) {
                float a = As[tr * 8 + i][kk];
                acc[i][0] = fmaf(a, w.x, acc[i][0]);
                acc[i][1] = fmaf(a, w.y, acc[i][1]);
                acc[i][2] = fmaf(a, w.z, acc[i][2]);
                acc[i][3] = fmaf(a, w.w, acc[i][3]);
            }
        }
        __syncthreads();
    }
    #pragma unroll
    for (int i = 0; i < 8; ++i) {
        int gr = row0 + tr * 8 + i;
        if (gr < n) {
            float4 v = make_float4(acc[i][0], acc[i][1], acc[i][2], acc[i][3]);
            *(float4*)&P[(long long)gr * 128 + tc * 4] = v;
        }
    }
}

// Layer 0: P = x @ W1[200:328] + W1[z] + W1[100+z]   (W1:[328,128])
__global__ __launch_bounds__(256) void k_embed(
    const float* __restrict__ X, const int* __restrict__ Z,
    const float* __restrict__ W1, float* __restrict__ P, int n)
{
    __shared__ float As[64][16];
    __shared__ float Ws[16][128];
    const int tid = threadIdx.x;
    const int tc = tid & 31, tr = tid >> 5;
    const int row0 = blockIdx.x * 64;
    const int lr = tid >> 2, lq = tid & 3;
    float acc[8][4] = {};
    for (int k0 = 0; k0 < 128; k0 += 16) {
        int gr = row0 + lr;
        float4 av = make_float4(0.f, 0.f, 0.f, 0.f);
        if (gr < n) av = *(const float4*)&X[(long long)gr * 128 + k0 + lq * 4];
        *(float4*)&As[lr][lq * 4] = av;
        #pragma unroll
        for (int s = 0; s < 2; ++s) {
            int idx = tid + s * 256;
            int r = idx >> 5, c = idx & 31;
            *(float4*)&Ws[r][c * 4] = *(const float4*)&W1[(200 + k0 + r) * 128 + c * 4];
        }
        __syncthreads();
        #pragma unroll
        for (int kk = 0; kk < 16; ++kk) {
            float4 w = *(const float4*)&Ws[kk][tc * 4];
            #pragma unroll
            for (int i = 0; i < 8; ++i) {
                float a = As[tr * 8 + i][kk];
                acc[i][0] = fmaf(a, w.x, acc[i][0]);
                acc[i][1] = fmaf(a, w.y, acc[i][1]);
                acc[i][2] = fmaf(a, w.z, acc[i][2]);
                acc[i][3] = fmaf(a, w.w, acc[i][3]);
            }
        }
        __syncthreads();
    }
    #pragma unroll
    for (int i = 0; i < 8; ++i) {
        int gr = row0 + tr * 8 + i;
        if (gr < n) {
            int zv = Z[gr];
            float4 w0 = *(const float4*)&W1[zv * 128 + tc * 4];
            float4 w1 = *(const float4*)&W1[(100 + zv) * 128 + tc * 4];
            float4 v = make_float4(acc[i][0] + w0.x + w1.x, acc[i][1] + w0.y + w1.y,
                                   acc[i][2] + w0.z + w1.z, acc[i][3] + w0.w + w1.w);
            *(float4*)&P[(long long)gr * 128 + tc * 4] = v;
        }
    }
}

// M[i] = relu( P[i] + sum_{j in N(i)} P[j] + b1 + (1+deg)*cvec )
// 32-lane team per node, lane q owns cols [4q,4q+4).
__global__ __launch_bounds__(256) void k_aggregate(
    const float* __restrict__ P, const int* __restrict__ row_start,
    const int* __restrict__ ssrc, const float* __restrict__ b1,
    const float* __restrict__ cvec, float* __restrict__ M)
{
    int idx = blockIdx.x * 256 + threadIdx.x;
    int node = idx >> 5, q = idx & 31;
    if (node >= NN) return;
    int s0 = row_start[node], s1 = row_start[node + 1];
    float degp1 = (float)(s1 - s0 + 1);
    float4 bv = *(const float4*)&b1[q * 4];
    float4 cv = *(const float4*)&cvec[q * 4];
    float4 pv = *(const float4*)&P[(long long)node * 128 + q * 4];
    float ax = pv.x + fmaf(degp1, cv.x, bv.x);
    float ay = pv.y + fmaf(degp1, cv.y, bv.y);
    float az = pv.z + fmaf(degp1, cv.z, bv.z);
    float aw = pv.w + fmaf(degp1, cv.w, bv.w);
    int e = s0;
    for (; e + 1 < s1; e += 2) {
        int sa = ssrc[e], sb = ssrc[e + 1];
        float4 va = *(const float4*)&P[(long long)sa * 128 + q * 4];
        float4 vb = *(const float4*)&P[(long long)sb * 128 + q * 4];
        ax += va.x + vb.x; ay += va.y + vb.y;
        az += va.z + vb.z; aw += va.w + vb.w;
    }
    if (e < s1) {
        int sa = ssrc[e];
        float4 va = *(const float4*)&P[(long long)sa * 128 + q * 4];
        ax += va.x; ay += va.y; az += va.z; aw += va.w;
    }
    float4 o = make_float4(fmaxf(ax, 0.f), fmaxf(ay, 0.f), fmaxf(az, 0.f), fmaxf(aw, 0.f));
    *(float4*)&M[(long long)node * 128 + q * 4] = o;
}

// A = relu( M @ W2 + b2 ); fused colsum/colsumsq for BN stats
__global__ __launch_bounds__(256) void k_gemm2(
    const float* __restrict__ M, float* __restrict__ A,
    const float* __restrict__ W2, const float* __restrict__ b2,
    float* __restrict__ colsum, float* __restrict__ colsq, int n)
{
    __shared__ float As[64][16];
    __shared__ float Ws[16][128];
    __shared__ float red[8][128];
    const int tid = threadIdx.x;
    const int tc = tid & 31, tr = tid >> 5;
    const int row0 = blockIdx.x * 64;
    const int lr = tid >> 2, lq = tid & 3;
    float acc[8][4] = {};
    for (int k0 = 0; k0 < 128; k0 += 16) {
        int gr = row0 + lr;
        float4 av = make_float4(0.f, 0.f, 0.f, 0.f);
        if (gr < n) av = *(const float4*)&M[(long long)gr * 128 + k0 + lq * 4];
        *(float4*)&As[lr][lq * 4] = av;
        #pragma unroll
        for (int s = 0; s < 2; ++s) {
            int idx = tid + s * 256;
            int r = idx >> 5, c = idx & 31;
            *(float4*)&Ws[r][c * 4] = *(const float4*)&W2[(k0 + r) * 128 + c * 4];
        }
        __syncthreads();
        #pragma unroll
        for (int kk = 0; kk < 16; ++kk) {
            float4 w = *(const float4*)&Ws[kk][tc * 4];
            #pragma unroll
            for (int i = 0; i < 8; ++i) {
                float a = As[tr * 8 + i][kk];
                acc[i][0] = fmaf(a, w.x, acc[i][0]);
                acc[i][1] = fmaf(a, w.y, acc[i][1]);
                acc[i][2] = fmaf(a, w.z, acc[i][2]);
                acc[i][3] = fmaf(a, w.w, acc[i][3]);
            }
        }
        __syncthreads();
    }
    float4 b2v = *(const float4*)&b2[tc * 4];
    float s_[4] = {0.f, 0.f, 0.f, 0.f};
    float q_[4] = {0.f, 0.f, 0.f, 0.f};
    #pragma unroll
    for (int i = 0; i < 8; ++i) {
        int gr = row0 + tr * 8 + i;
        if (gr < n) {
            float4 v;
            v.x = fmaxf(acc[i][0] + b2v.x, 0.f);
            v.y = fmaxf(acc[i][1] + b2v.y, 0.f);
            v.z = fmaxf(acc[i][2] + b2v.z, 0.f);
            v.w = fmaxf(acc[i][3] + b2v.w, 0.f);
            *(float4*)&A[(long long)gr * 128 + tc * 4] = v;
            s_[0] += v.x; s_[1] += v.y; s_[2] += v.z; s_[3] += v.w;
            q_[0] += v.x * v.x; q_[1] += v.y * v.y; q_[2] += v.z * v.z; q_[3] += v.w * v.w;
        }
    }
    __syncthreads();
    #pragma unroll
    for (int j = 0; j < 4; ++j) red[tr][tc * 4 + j] = s_[j];
    __syncthreads();
    if (tid < 128) {
        float t = 0.f;
        #pragma unroll
        for (int r = 0; r < 8; ++r) t += red[r][tid];
        atomicAdd(&colsum[tid], t);
    }
    __syncthreads();
    #pragma unroll
    for (int j = 0; j < 4; ++j) red[tr][tc * 4 + j] = q_[j];
    __syncthreads();
    if (tid < 128) {
        float t = 0.f;
        #pragma unroll
        for (int r = 0; r < 8; ++r) t += red[r][tid];
        atomicAdd(&colsq[tid], t);
    }
}

__global__ void k_bnfin(const float* __restrict__ colsum, const float* __restrict__ colsq,
                        const float* __restrict__ g, const float* __restrict__ be,
                        float* __restrict__ scale, float* __restrict__ shift)
{
    int c = threadIdx.x;
    float inv_n = 1.0f / (float)NN;
    float mu = colsum[c] * inv_n;
    float var = colsq[c] * inv_n - mu * mu;
    float sc = g[c] * rsqrtf(var + BN_EPS);
    scale[c] = sc;
    shift[c] = be[c] - mu * sc;
}

// mean-pool per graph with BN applied on the fly: pooled = sc*mean(A) + sh
__global__ __launch_bounds__(128) void k_pool(
    const float* __restrict__ A, const int* __restrict__ batch,
    const float* __restrict__ scale, const float* __restrict__ shift,
    float* __restrict__ pooled, int loff)
{
    int g = blockIdx.x;
    int c = threadIdx.x;
    int lo = 0, hi = NN;
    while (lo < hi) { int mid = (lo + hi) >> 1; if (batch[mid] < g) lo = mid + 1; else hi = mid; }
    int s = lo;
    lo = s; hi = NN;
    while (lo < hi) { int mid = (lo + hi) >> 1; if (batch[mid] < g + 1) lo = mid + 1; else hi = mid; }
    int e = lo;
    float acc = 0.f;
    for (int i = s; i < e; ++i) acc += A[(long long)i * 128 + c];
    int cnt = e - s;
    float mean = acc / (float)(cnt > 0 ? cnt : 1);
    pooled[g * 384 + loff + c] = fmaf(scale[c], mean, shift[c]);
}

// out[g] = relu(pooled[g] @ Wl1 + bl1) @ Wl2 + bl2
__global__ __launch_bounds__(128) void k_final(
    const float* __restrict__ pooled,
    const float* __restrict__ Wl1, const float* __restrict__ bl1,
    const float* __restrict__ Wl2, const float* __restrict__ bl2,
    float* __restrict__ out)
{
    __shared__ float pr[384];
    __shared__ float red[128];
    int g = blockIdx.x, j = threadIdx.x;
    for (int i = j; i < 384; i += 128) pr[i] = pooled[g * 384 + i];
    __syncthreads();
    float acc = bl1[j];
    for (int k = 0; k < 384; ++k) acc = fmaf(pr[k], Wl1[k * 128 + j], acc);
    float r = fmaxf(acc, 0.f) * Wl2[j];
    red[j] = r;
    __syncthreads();
    for (int off = 64; off > 0; off >>= 1) {
        if (j < off) red[j] += red[j + off];
        __syncthreads();
    }
    if (j == 0) out[g] = red[0] + bl2[0];
}

extern "C" void kernel_launch(void* const* d_in, const int* in_sizes, int n_in,
                              void* d_out, int out_size, void* d_ws, size_t ws_size,
                              hipStream_t stream)
{
    const float* x     = (const float*)d_in[0];
    const int*   z     = (const int*)d_in[1];
    const int*   ei    = (const int*)d_in[2];
    const int*   batch = (const int*)d_in[3];
    const float* W1a[3] = {(const float*)d_in[4],  (const float*)d_in[10], (const float*)d_in[16]};
    const float* b1a[3] = {(const float*)d_in[5],  (const float*)d_in[11], (const float*)d_in[17]};
    const float* W2a[3] = {(const float*)d_in[6],  (const float*)d_in[12], (const float*)d_in[18]};
    const float* b2a[3] = {(const float*)d_in[7],  (const float*)d_in[13], (const float*)d_in[19]};
    const float* ga[3]  = {(const float*)d_in[8],  (const float*)d_in[14], (const float*)d_in[20]};
    const float* bea[3] = {(const float*)d_in[9],  (const float*)d_in[15], (const float*)d_in[21]};
    const float* Wl1 = (const float*)d_in[22];
    const float* bl1 = (const float*)d_in[23];
    const float* Wl2 = (const float*)d_in[24];
    const float* bl2 = (const float*)d_in[25];
    float* out = (float*)d_out;

    char* ws = (char*)d_ws;
    size_t off = 0;
    auto alloc = [&](size_t bytes) {
        void* p = ws + off;
        off += (bytes + 255) & ~(size_t)255;
        return p;
    };
    float* P        = (float*)alloc((size_t)NN * 128 * 4);   // projections
    float* M        = (float*)alloc((size_t)NN * 128 * 4);   // aggregated+relu
    float* A        = (float*)alloc((size_t)NN * 128 * 4);   // activations (pre-BN)
    int*   hist     = (int*)alloc((size_t)NN * 4);
    int*   row_st   = (int*)alloc((size_t)(NN + 1) * 4);
    int*   cursor   = (int*)alloc((size_t)NN * 4);
    int*   ssrc     = (int*)alloc((size_t)EE * 4);
    int*   partials = (int*)alloc((size_t)SCAN_BLOCKS * 4);
    int*   poffs    = (int*)alloc((size_t)SCAN_BLOCKS * 4);
    float* W1f      = (float*)alloc(128 * 128 * 4);
    float* cvec     = (float*)alloc(128 * 4);
    float* cvec0    = (float*)alloc(128 * 4);
    float* colsum   = (float*)alloc(128 * 4);
    float* colsq    = (float*)alloc(128 * 4);
    float* scale    = (float*)alloc(128 * 4);
    float* shift    = (float*)alloc(128 * 4);
    float* pooled   = (float*)alloc((size_t)GG * 384 * 4);

    const int gemmBlocks = (NN + 63) / 64;
    const int edgeBlocks = (EE + 255) / 256;
    const int aggBlocks  = (NN * 32 + 255) / 256;

    // ---- CSR build (once per call) ----
    hipMemsetAsync(hist, 0, (size_t)NN * 4, stream);
    hipMemsetAsync(cvec0, 0, 128 * 4, stream);
    k_hist<<<edgeBlocks, 256, 0, stream>>>(ei, hist);
    k_scan1<<<SCAN_BLOCKS, 256, 0, stream>>>(hist, partials);
    k_scan2<<<1, 256, 0, stream>>>(partials, poffs, row_st);
    k_scan3<<<SCAN_BLOCKS, 256, 0, stream>>>(hist, poffs, row_st, cursor);
    k_fill<<<edgeBlocks, 256, 0, stream>>>(ei, cursor, ssrc);

    for (int l = 0; l < 3; ++l) {
        hipMemsetAsync(colsum, 0, 128 * 4, stream);
        hipMemsetAsync(colsq, 0, 128 * 4, stream);
        const float* cv = cvec0;
        if (l == 0) {
            k_embed<<<gemmBlocks, 256, 0, stream>>>(x, z, W1a[0], P, NN);
        } else {
            // fold previous layer's BN (scale/shift) into W1
            k_foldW<<<64, 256, 0, stream>>>(W1a[l], scale, W1f);
            k_cvec<<<1, 128, 0, stream>>>(W1a[l], shift, cvec);
            k_gemm1<<<gemmBlocks, 256, 0, stream>>>(A, W1f, P, NN);
            cv = cvec;
        }
        k_aggregate<<<aggBlocks, 256, 0, stream>>>(P, row_st, ssrc, b1a[l], cv, M);
        k_gemm2<<<gemmBlocks, 256, 0, stream>>>(M, A, W2a[l], b2a[l], colsum, colsq, NN);
        k_bnfin<<<1, 128, 0, stream>>>(colsum, colsq, ga[l], bea[l], scale, shift);
        k_pool<<<GG, 128, 0, stream>>>(A, batch, scale, shift, pooled, l * 128);
    }
    k_final<<<GG, 128, 0, stream>>>(pooled, Wl1, bl1, Wl2, bl2, out);
}

// Round 4
// 1147.771 us; speedup vs baseline: 7.6878x; 1.0992x over previous
//
#include <hip/hip_runtime.h>
#include <hip/hip_bf16.h>

#define NN 100000
#define EE 1600000
#define GG 512
#define SCAN_CHUNK 512
#define SCAN_BLOCKS ((NN + SCAN_CHUNK - 1) / SCAN_CHUNK)   // 196
#define NPB 256                                            // nodes per bucket
#define NB  ((NN + NPB - 1) / NPB)                         // 391 buckets
#define PCHUNK 4096                                        // edges per partition block
#define PBLOCKS ((EE + PCHUNK - 1) / PCHUNK)               // 391
static constexpr float BN_EPS = 1e-5f;

// ---------------------------------------------------------------------------
// CSR build, write-local:
//   bhist -> bscan -> part (bucket-partition edges) -> nhist -> scan -> fill2
// ---------------------------------------------------------------------------

// coarse bucket histogram (LDS-aggregated)
__global__ __launch_bounds__(256) void k_bhist(const int* __restrict__ EI,
                                               int* __restrict__ bcount)
{
    __shared__ int h[NB];
    const int t = threadIdx.x;
    for (int i = t; i < NB; i += 256) h[i] = 0;
    __syncthreads();
    const int e0 = blockIdx.x * PCHUNK;
    const int e1 = (e0 + PCHUNK < EE) ? e0 + PCHUNK : EE;
    for (int e = e0 + t; e < e1; e += 256)
        atomicAdd(&h[EI[EE + e] >> 8], 1);
    __syncthreads();
    for (int i = t; i < NB; i += 256)
        if (h[i]) atomicAdd(&bcount[i], h[i]);
}

// exclusive scan of 391 bucket counts -> bstart[NB+1], bcursor
__global__ __launch_bounds__(512) void k_bscan(const int* __restrict__ bcount,
                                               int* __restrict__ bstart,
                                               int* __restrict__ bcursor)
{
    __shared__ int s[512];
    int t = threadIdx.x;
    int v = (t < NB) ? bcount[t] : 0;
    s[t] = v;
    __syncthreads();
    for (int off = 1; off < 512; off <<= 1) {
        int u = (t >= off) ? s[t - off] : 0;
        __syncthreads();
        s[t] += u;
        __syncthreads();
    }
    if (t < NB) { int ex = s[t] - v; bstart[t] = ex; bcursor[t] = ex; }
    if (t == 0) bstart[NB] = EE;
}

// partition edges into bucket-contiguous ebuf[(src,dst)] with block-aggregated
// reservations: LDS hist -> 1 global atomic per (block,bucket) -> LDS cursors.
__global__ __launch_bounds__(256) void k_part(const int* __restrict__ EI,
                                              int* __restrict__ bcursor,
                                              int2* __restrict__ ebuf)
{
    __shared__ int h[NB];
    __shared__ int cur[NB];
    const int t = threadIdx.x;
    for (int i = t; i < NB; i += 256) h[i] = 0;
    __syncthreads();
    const int e0 = blockIdx.x * PCHUNK;
    const int e1 = (e0 + PCHUNK < EE) ? e0 + PCHUNK : EE;
    for (int e = e0 + t; e < e1; e += 256)
        atomicAdd(&h[EI[EE + e] >> 8], 1);
    __syncthreads();
    for (int i = t; i < NB; i += 256)
        cur[i] = h[i] ? atomicAdd(&bcursor[i], h[i]) : 0;
    __syncthreads();
    for (int e = e0 + t; e < e1; e += 256) {
        int s = EI[e], d = EI[EE + e];
        int pos = atomicAdd(&cur[d >> 8], 1);
        ebuf[pos] = make_int2(s, d);
    }
}

// per-node histogram from partitioned edges (LDS counters, plain stores)
__global__ __launch_bounds__(256) void k_nhist(const int2* __restrict__ ebuf,
                                               const int* __restrict__ bstart,
                                               int* __restrict__ hist)
{
    __shared__ int cnt[NPB];
    const int b = blockIdx.x, t = threadIdx.x;
    cnt[t] = 0;
    __syncthreads();
    const int e0 = bstart[b], e1 = bstart[b + 1];
    for (int e = e0 + t; e < e1; e += 256)
        atomicAdd(&cnt[ebuf[e].y & (NPB - 1)], 1);
    __syncthreads();
    int idx = b * NPB + t;
    if (idx < NN) hist[idx] = cnt[t];
}

// 3-phase scan of per-node counts -> row_start
__global__ __launch_bounds__(256) void k_scan1(const int* __restrict__ hist,
                                               int* __restrict__ partials)
{
    __shared__ int red[256];
    int b = blockIdx.x, t = threadIdx.x;
    int i0 = b * SCAN_CHUNK + 2 * t;
    int e0 = (i0 < NN) ? hist[i0] : 0;
    int e1 = (i0 + 1 < NN) ? hist[i0 + 1] : 0;
    red[t] = e0 + e1;
    __syncthreads();
    for (int off = 128; off > 0; off >>= 1) {
        if (t < off) red[t] += red[t + off];
        __syncthreads();
    }
    if (t == 0) partials[b] = red[0];
}

__global__ __launch_bounds__(256) void k_scan2(const int* __restrict__ partials,
                                               int* __restrict__ poffs,
                                               int* __restrict__ row_start)
{
    __shared__ int s[256];
    int t = threadIdx.x;
    int v = (t < SCAN_BLOCKS) ? partials[t] : 0;
    s[t] = v;
    __syncthreads();
    for (int off = 1; off < 256; off <<= 1) {
        int u = (t >= off) ? s[t - off] : 0;
        __syncthreads();
        s[t] += u;
        __syncthreads();
    }
    if (t < SCAN_BLOCKS) poffs[t] = s[t] - v;
    if (t == 0) row_start[NN] = EE;
}

__global__ __launch_bounds__(256) void k_scan3(const int* __restrict__ hist,
                                               const int* __restrict__ poffs,
                                               int* __restrict__ row_start)
{
    __shared__ int s[256];
    int b = blockIdx.x, t = threadIdx.x;
    int i0 = b * SCAN_CHUNK + 2 * t;
    int e0 = (i0 < NN) ? hist[i0] : 0;
    int e1 = (i0 + 1 < NN) ? hist[i0 + 1] : 0;
    int pair = e0 + e1;
    s[t] = pair;
    __syncthreads();
    for (int off = 1; off < 256; off <<= 1) {
        int u = (t >= off) ? s[t - off] : 0;
        __syncthreads();
        s[t] += u;
        __syncthreads();
    }
    int base = poffs[b] + s[t] - pair;
    if (i0 < NN)     row_start[i0] = base;
    if (i0 + 1 < NN) row_start[i0 + 1] = base + e0;
}

// final CSR fill: block per bucket, LDS cursors, writes confined to the
// bucket's contiguous row_start window.
__global__ __launch_bounds__(256) void k_fill2(const int2* __restrict__ ebuf,
                                               const int* __restrict__ bstart,
                                               const int* __restrict__ row_start,
                                               int* __restrict__ ssrc)
{
    __shared__ int cur[NPB];
    const int b = blockIdx.x, t = threadIdx.x;
    int idx = b * NPB + t;
    cur[t] = (idx < NN) ? row_start[idx] : 0;
    __syncthreads();
    const int e0 = bstart[b], e1 = bstart[b + 1];
    for (int e = e0 + t; e < e1; e += 256) {
        int2 ed = ebuf[e];
        int pos = atomicAdd(&cur[ed.y & (NPB - 1)], 1);
        ssrc[pos] = ed.x;
    }
}

// ---------------------------------------------------------------------------
// BN folding: W1f[k][j] = scale[k]*W1[k][j];  cvec[j] = sum_k shift[k]*W1[k][j]
// ---------------------------------------------------------------------------

__global__ __launch_bounds__(256) void k_foldW(const float* __restrict__ W1,
                                               const float* __restrict__ scale,
                                               float* __restrict__ W1f)
{
    int idx = blockIdx.x * 256 + threadIdx.x;
    int k = idx >> 7;
    W1f[idx] = scale[k] * W1[idx];
}

__global__ __launch_bounds__(128) void k_cvec(const float* __restrict__ W1,
                                              const float* __restrict__ shift,
                                              float* __restrict__ cvec)
{
    int j = threadIdx.x;
    float acc = 0.f;
    for (int k = 0; k < 128; ++k) acc = fmaf(shift[k], W1[k * 128 + j], acc);
    cvec[j] = acc;
}

// ---------------------------------------------------------------------------
// GEMMs: 64 rows x 128 cols per block, 256 threads, K-chunks of 16.
// ---------------------------------------------------------------------------

__global__ __launch_bounds__(256) void k_gemm1(
    const float* __restrict__ A, const float* __restrict__ W,
    float* __restrict__ P, int n)
{
    __shared__ float As[64][16];
    __shared__ float Ws[16][128];
    const int tid = threadIdx.x;
    const int tc = tid & 31, tr = tid >> 5;
    const int row0 = blockIdx.x * 64;
    const int lr = tid >> 2, lq = tid & 3;
    float acc[8][4] = {};
    for (int k0 = 0; k0 < 128; k0 += 16) {
        int gr = row0 + lr;
        float4 av = make_float4(0.f, 0.f, 0.f, 0.f);
        if (gr < n) av = *(const float4*)&A[(long long)gr * 128 + k0 + lq * 4];
        *(float4*)&As[lr][lq * 4] = av;
        #pragma unroll
        for (int s = 0; s < 2; ++s) {
            int idx = tid + s * 256;
            int r = idx >> 5, c = idx & 31;
            *(float4*)&Ws[r][c * 4] = *(const float4*)&W[(k0 + r) * 128 + c * 4];
        }
        __syncthreads();
        #pragma unroll
        for (int kk = 0; kk < 16; ++kk) {
            float4 w = *(const float4*)&Ws[kk][tc * 4];
            #pragma unroll
            for (int i = 0; i < 8; ++i) {
                float a = As[tr * 8 + i][kk];
                acc[i][0] = fmaf(a, w.x, acc[i][0]);
                acc[i][1] = fmaf(a, w.y, acc[i][1]);
                acc[i][2] = fmaf(a, w.z, acc[i][2]);
                acc[i][3] = fmaf(a, w.w, acc[i][3]);
            }
        }
        __syncthreads();
    }
    #pragma unroll
    for (int i = 0; i < 8; ++i) {
        int gr = row0 + tr * 8 + i;
        if (gr < n) {
            float4 v = make_float4(acc[i][0], acc[i][1], acc[i][2], acc[i][3]);
            *(float4*)&P[(long long)gr * 128 + tc * 4] = v;
        }
    }
}

__global__ __launch_bounds__(256) void k_embed(
    const float* __restrict__ X, const int* __restrict__ Z,
    const float* __restrict__ W1, float* __restrict__ P, int n)
{
    __shared__ float As[64][16];
    __shared__ float Ws[16][128];
    const int tid = threadIdx.x;
    const int tc = tid & 31, tr = tid >> 5;
    const int row0 = blockIdx.x * 64;
    const int lr = tid >> 2, lq = tid & 3;
    float acc[8][4] = {};
    for (int k0 = 0; k0 < 128; k0 += 16) {
        int gr = row0 + lr;
        float4 av = make_float4(0.f, 0.f, 0.f, 0.f);
        if (gr < n) av = *(const float4*)&X[(long long)gr * 128 + k0 + lq * 4];
        *(float4*)&As[lr][lq * 4] = av;
        #pragma unroll
        for (int s = 0; s < 2; ++s) {
            int idx = tid + s * 256;
            int r = idx >> 5, c = idx & 31;
            *(float4*)&Ws[r][c * 4] = *(const float4*)&W1[(200 + k0 + r) * 128 + c * 4];
        }
        __syncthreads();
        #pragma unroll
        for (int kk = 0; kk < 16; ++kk) {
            float4 w = *(const float4*)&Ws[kk][tc * 4];
            #pragma unroll
            for (int i = 0; i < 8; ++i) {
                float a = As[tr * 8 + i][kk];
                acc[i][0] = fmaf(a, w.x, acc[i][0]);
                acc[i][1] = fmaf(a, w.y, acc[i][1]);
                acc[i][2] = fmaf(a, w.z, acc[i][2]);
                acc[i][3] = fmaf(a, w.w, acc[i][3]);
            }
        }
        __syncthreads();
    }
    #pragma unroll
    for (int i = 0; i < 8; ++i) {
        int gr = row0 + tr * 8 + i;
        if (gr < n) {
            int zv = Z[gr];
            float4 w0 = *(const float4*)&W1[zv * 128 + tc * 4];
            float4 w1 = *(const float4*)&W1[(100 + zv) * 128 + tc * 4];
            float4 v = make_float4(acc[i][0] + w0.x + w1.x, acc[i][1] + w0.y + w1.y,
                                   acc[i][2] + w0.z + w1.z, acc[i][3] + w0.w + w1.w);
            *(float4*)&P[(long long)gr * 128 + tc * 4] = v;
        }
    }
}

// M[i] = relu( P[i] + sum_{j in N(i)} P[j] + b1 + (1+deg)*cvec )
__global__ __launch_bounds__(256) void k_aggregate(
    const float* __restrict__ P, const int* __restrict__ row_start,
    const int* __restrict__ ssrc, const float* __restrict__ b1,
    const float* __restrict__ cvec, float* __restrict__ M)
{
    int idx = blockIdx.x * 256 + threadIdx.x;
    int node = idx >> 5, q = idx & 31;
    if (node >= NN) return;
    int s0 = row_start[node], s1 = row_start[node + 1];
    float degp1 = (float)(s1 - s0 + 1);
    float4 bv = *(const float4*)&b1[q * 4];
    float4 cv = *(const float4*)&cvec[q * 4];
    float4 pv = *(const float4*)&P[(long long)node * 128 + q * 4];
    float ax = pv.x + fmaf(degp1, cv.x, bv.x);
    float ay = pv.y + fmaf(degp1, cv.y, bv.y);
    float az = pv.z + fmaf(degp1, cv.z, bv.z);
    float aw = pv.w + fmaf(degp1, cv.w, bv.w);
    int e = s0;
    for (; e + 1 < s1; e += 2) {
        int sa = ssrc[e], sb = ssrc[e + 1];
        float4 va = *(const float4*)&P[(long long)sa * 128 + q * 4];
        float4 vb = *(const float4*)&P[(long long)sb * 128 + q * 4];
        ax += va.x + vb.x; ay += va.y + vb.y;
        az += va.z + vb.z; aw += va.w + vb.w;
    }
    if (e < s1) {
        int sa = ssrc[e];
        float4 va = *(const float4*)&P[(long long)sa * 128 + q * 4];
        ax += va.x; ay += va.y; az += va.z; aw += va.w;
    }
    float4 o = make_float4(fmaxf(ax, 0.f), fmaxf(ay, 0.f), fmaxf(az, 0.f), fmaxf(aw, 0.f));
    *(float4*)&M[(long long)node * 128 + q * 4] = o;
}

// A = relu( M @ W2 + b2 ); fused colsum/colsumsq for BN stats
__global__ __launch_bounds__(256) void k_gemm2(
    const float* __restrict__ M, float* __restrict__ A,
    const float* __restrict__ W2, const float* __restrict__ b2,
    float* __restrict__ colsum, float* __restrict__ colsq, int n)
{
    __shared__ float As[64][16];
    __shared__ float Ws[16][128];
    __shared__ float red[8][128];
    const int tid = threadIdx.x;
    const int tc = tid & 31, tr = tid >> 5;
    const int row0 = blockIdx.x * 64;
    const int lr = tid >> 2, lq = tid & 3;
    float acc[8][4] = {};
    for (int k0 = 0; k0 < 128; k0 += 16) {
        int gr = row0 + lr;
        float4 av = make_float4(0.f, 0.f, 0.f, 0.f);
        if (gr < n) av = *(const float4*)&M[(long long)gr * 128 + k0 + lq * 4];
        *(float4*)&As[lr][lq * 4] = av;
        #pragma unroll
        for (int s = 0; s < 2; ++s) {
            int idx = tid + s * 256;
            int r = idx >> 5, c = idx & 31;
            *(float4*)&Ws[r][c * 4] = *(const float4*)&W2[(k0 + r) * 128 + c * 4];
        }
        __syncthreads();
        #pragma unroll
        for (int kk = 0; kk < 16; ++kk) {
            float4 w = *(const float4*)&Ws[kk][tc * 4];
            #pragma unroll
            for (int i = 0; i < 8; ++i) {
                float a = As[tr * 8 + i][kk];
                acc[i][0] = fmaf(a, w.x, acc[i][0]);
                acc[i][1] = fmaf(a, w.y, acc[i][1]);
                acc[i][2] = fmaf(a, w.z, acc[i][2]);
                acc[i][3] = fmaf(a, w.w, acc[i][3]);
            }
        }
        __syncthreads();
    }
    float4 b2v = *(const float4*)&b2[tc * 4];
    float s_[4] = {0.f, 0.f, 0.f, 0.f};
    float q_[4] = {0.f, 0.f, 0.f, 0.f};
    #pragma unroll
    for (int i = 0; i < 8; ++i) {
        int gr = row0 + tr * 8 + i;
        if (gr < n) {
            float4 v;
            v.x = fmaxf(acc[i][0] + b2v.x, 0.f);
            v.y = fmaxf(acc[i][1] + b2v.y, 0.f);
            v.z = fmaxf(acc[i][2] + b2v.z, 0.f);
            v.w = fmaxf(acc[i][3] + b2v.w, 0.f);
            *(float4*)&A[(long long)gr * 128 + tc * 4] = v;
            s_[0] += v.x; s_[1] += v.y; s_[2] += v.z; s_[3] += v.w;
            q_[0] += v.x * v.x; q_[1] += v.y * v.y; q_[2] += v.z * v.z; q_[3] += v.w * v.w;
        }
    }
    __syncthreads();
    #pragma unroll
    for (int j = 0; j < 4; ++j) red[tr][tc * 4 + j] = s_[j];
    __syncthreads();
    if (tid < 128) {
        float t = 0.f;
        #pragma unroll
        for (int r = 0; r < 8; ++r) t += red[r][tid];
        atomicAdd(&colsum[tid], t);
    }
    __syncthreads();
    #pragma unroll
    for (int j = 0; j < 4; ++j) red[tr][tc * 4 + j] = q_[j];
    __syncthreads();
    if (tid < 128) {
        float t = 0.f;
        #pragma unroll
        for (int r = 0; r < 8; ++r) t += red[r][tid];
        atomicAdd(&colsq[tid], t);
    }
}

__global__ void k_bnfin(const float* __restrict__ colsum, const float* __restrict__ colsq,
                        const float* __restrict__ g, const float* __restrict__ be,
                        float* __restrict__ scale, float* __restrict__ shift)
{
    int c = threadIdx.x;
    float inv_n = 1.0f / (float)NN;
    float mu = colsum[c] * inv_n;
    float var = colsq[c] * inv_n - mu * mu;
    float sc = g[c] * rsqrtf(var + BN_EPS);
    scale[c] = sc;
    shift[c] = be[c] - mu * sc;
}

// mean-pool per graph with BN applied on the fly
__global__ __launch_bounds__(128) void k_pool(
    const float* __restrict__ A, const int* __restrict__ batch,
    const float* __restrict__ scale, const float* __restrict__ shift,
    float* __restrict__ pooled, int loff)
{
    int g = blockIdx.x;
    int c = threadIdx.x;
    int lo = 0, hi = NN;
    while (lo < hi) { int mid = (lo + hi) >> 1; if (batch[mid] < g) lo = mid + 1; else hi = mid; }
    int s = lo;
    lo = s; hi = NN;
    while (lo < hi) { int mid = (lo + hi) >> 1; if (batch[mid] < g + 1) lo = mid + 1; else hi = mid; }
    int e = lo;
    float acc = 0.f;
    for (int i = s; i < e; ++i) acc += A[(long long)i * 128 + c];
    int cnt = e - s;
    float mean = acc / (float)(cnt > 0 ? cnt : 1);
    pooled[g * 384 + loff + c] = fmaf(scale[c], mean, shift[c]);
}

__global__ __launch_bounds__(128) void k_final(
    const float* __restrict__ pooled,
    const float* __restrict__ Wl1, const float* __restrict__ bl1,
    const float* __restrict__ Wl2, const float* __restrict__ bl2,
    float* __restrict__ out)
{
    __shared__ float pr[384];
    __shared__ float red[128];
    int g = blockIdx.x, j = threadIdx.x;
    for (int i = j; i < 384; i += 128) pr[i] = pooled[g * 384 + i];
    __syncthreads();
    float acc = bl1[j];
    for (int k = 0; k < 384; ++k) acc = fmaf(pr[k], Wl1[k * 128 + j], acc);
    float r = fmaxf(acc, 0.f) * Wl2[j];
    red[j] = r;
    __syncthreads();
    for (int off = 64; off > 0; off >>= 1) {
        if (j < off) red[j] += red[j + off];
        __syncthreads();
    }
    if (j == 0) out[g] = red[0] + bl2[0];
}

extern "C" void kernel_launch(void* const* d_in, const int* in_sizes, int n_in,
                              void* d_out, int out_size, void* d_ws, size_t ws_size,
                              hipStream_t stream)
{
    const float* x     = (const float*)d_in[0];
    const int*   z     = (const int*)d_in[1];
    const int*   ei    = (const int*)d_in[2];
    const int*   batch = (const int*)d_in[3];
    const float* W1a[3] = {(const float*)d_in[4],  (const float*)d_in[10], (const float*)d_in[16]};
    const float* b1a[3] = {(const float*)d_in[5],  (const float*)d_in[11], (const float*)d_in[17]};
    const float* W2a[3] = {(const float*)d_in[6],  (const float*)d_in[12], (const float*)d_in[18]};
    const float* b2a[3] = {(const float*)d_in[7],  (const float*)d_in[13], (const float*)d_in[19]};
    const float* ga[3]  = {(const float*)d_in[8],  (const float*)d_in[14], (const float*)d_in[20]};
    const float* bea[3] = {(const float*)d_in[9],  (const float*)d_in[15], (const float*)d_in[21]};
    const float* Wl1 = (const float*)d_in[22];
    const float* bl1 = (const float*)d_in[23];
    const float* Wl2 = (const float*)d_in[24];
    const float* bl2 = (const float*)d_in[25];
    float* out = (float*)d_out;

    char* ws = (char*)d_ws;
    size_t off = 0;
    auto alloc = [&](size_t bytes) {
        void* p = ws + off;
        off += (bytes + 255) & ~(size_t)255;
        return p;
    };
    float* P        = (float*)alloc((size_t)NN * 128 * 4);
    float* M        = (float*)alloc((size_t)NN * 128 * 4);
    float* A        = (float*)alloc((size_t)NN * 128 * 4);
    int2*  ebuf     = (int2*)alloc((size_t)EE * 8);
    int*   ssrc     = (int*)alloc((size_t)EE * 4);
    int*   hist     = (int*)alloc((size_t)NN * 4);
    int*   row_st   = (int*)alloc((size_t)(NN + 1) * 4);
    int*   bcount   = (int*)alloc((size_t)NB * 4);
    int*   bstart   = (int*)alloc((size_t)(NB + 1) * 4);
    int*   bcursor  = (int*)alloc((size_t)NB * 4);
    int*   partials = (int*)alloc((size_t)SCAN_BLOCKS * 4);
    int*   poffs    = (int*)alloc((size_t)SCAN_BLOCKS * 4);
    float* W1f      = (float*)alloc(128 * 128 * 4);
    float* cvec     = (float*)alloc(128 * 4);
    float* cvec0    = (float*)alloc(128 * 4);
    float* colsum   = (float*)alloc(128 * 4);
    float* colsq    = (float*)alloc(128 * 4);
    float* scale    = (float*)alloc(128 * 4);
    float* shift    = (float*)alloc(128 * 4);
    float* pooled   = (float*)alloc((size_t)GG * 384 * 4);

    const int gemmBlocks = (NN + 63) / 64;
    const int aggBlocks  = (NN * 32 + 255) / 256;

    // ---- CSR build (write-local, once per call) ----
    hipMemsetAsync(bcount, 0, (size_t)NB * 4, stream);
    hipMemsetAsync(cvec0, 0, 128 * 4, stream);
    k_bhist<<<PBLOCKS, 256, 0, stream>>>(ei, bcount);
    k_bscan<<<1, 512, 0, stream>>>(bcount, bstart, bcursor);
    k_part<<<PBLOCKS, 256, 0, stream>>>(ei, bcursor, ebuf);
    k_nhist<<<NB, 256, 0, stream>>>(ebuf, bstart, hist);
    k_scan1<<<SCAN_BLOCKS, 256, 0, stream>>>(hist, partials);
    k_scan2<<<1, 256, 0, stream>>>(partials, poffs, row_st);
    k_scan3<<<SCAN_BLOCKS, 256, 0, stream>>>(hist, poffs, row_st);
    k_fill2<<<NB, 256, 0, stream>>>(ebuf, bstart, row_st, ssrc);

    for (int l = 0; l < 3; ++l) {
        hipMemsetAsync(colsum, 0, 128 * 4, stream);
        hipMemsetAsync(colsq, 0, 128 * 4, stream);
        const float* cv = cvec0;
        if (l == 0) {
            k_embed<<<gemmBlocks, 256, 0, stream>>>(x, z, W1a[0], P, NN);
        } else {
            k_foldW<<<64, 256, 0, stream>>>(W1a[l], scale, W1f);
            k_cvec<<<1, 128, 0, stream>>>(W1a[l], shift, cvec);
            k_gemm1<<<gemmBlocks, 256, 0, stream>>>(A, W1f, P, NN);
            cv = cvec;
        }
        k_aggregate<<<aggBlocks, 256, 0, stream>>>(P, row_st, ssrc, b1a[l], cv, M);
        k_gemm2<<<gemmBlocks, 256, 0, stream>>>(M, A, W2a[l], b2a[l], colsum, colsq, NN);
        k_bnfin<<<1, 128, 0, stream>>>(colsum, colsq, ga[l], bea[l], scale, shift);
        k_pool<<<GG, 128, 0, stream>>>(A, batch, scale, shift, pooled, l * 128);
    }
    k_final<<<GG, 128, 0, stream>>>(pooled, Wl1, bl1, Wl2, bl2, out);
}

// Round 5
// 926.053 us; speedup vs baseline: 9.5285x; 1.2394x over previous
//
#include <hip/hip_runtime.h>
#include <hip/hip_bf16.h>

#define NN 100000
#define NROWS_PAD 100032
#define EE 1600000
#define GG 512
#define SCAN_CHUNK 512
#define SCAN_BLOCKS ((NN + SCAN_CHUNK - 1) / SCAN_CHUNK)   // 196
#define NPB 256                                            // nodes per bucket
#define NB  ((NN + NPB - 1) / NPB)                         // 391 buckets
#define PCHUNK 4096                                        // edges per partition block
#define PBLOCKS ((EE + PCHUNK - 1) / PCHUNK)               // 391
static constexpr float BN_EPS = 1e-5f;

typedef _Float16 half8 __attribute__((ext_vector_type(8)));
typedef _Float16 half4 __attribute__((ext_vector_type(4)));
typedef float floatx4 __attribute__((ext_vector_type(4)));

// ---------------------------------------------------------------------------
// CSR build (write-local) — unchanged from R4
// ---------------------------------------------------------------------------

__global__ __launch_bounds__(256) void k_bhist(const int* __restrict__ EI,
                                               int* __restrict__ bcount)
{
    __shared__ int h[NB];
    const int t = threadIdx.x;
    for (int i = t; i < NB; i += 256) h[i] = 0;
    __syncthreads();
    const int e0 = blockIdx.x * PCHUNK;
    const int e1 = (e0 + PCHUNK < EE) ? e0 + PCHUNK : EE;
    for (int e = e0 + t; e < e1; e += 256)
        atomicAdd(&h[EI[EE + e] >> 8], 1);
    __syncthreads();
    for (int i = t; i < NB; i += 256)
        if (h[i]) atomicAdd(&bcount[i], h[i]);
}

__global__ __launch_bounds__(512) void k_bscan(const int* __restrict__ bcount,
                                               int* __restrict__ bstart,
                                               int* __restrict__ bcursor)
{
    __shared__ int s[512];
    int t = threadIdx.x;
    int v = (t < NB) ? bcount[t] : 0;
    s[t] = v;
    __syncthreads();
    for (int off = 1; off < 512; off <<= 1) {
        int u = (t >= off) ? s[t - off] : 0;
        __syncthreads();
        s[t] += u;
        __syncthreads();
    }
    if (t < NB) { int ex = s[t] - v; bstart[t] = ex; bcursor[t] = ex; }
    if (t == 0) bstart[NB] = EE;
}

__global__ __launch_bounds__(256) void k_part(const int* __restrict__ EI,
                                              int* __restrict__ bcursor,
                                              int2* __restrict__ ebuf)
{
    __shared__ int h[NB];
    __shared__ int cur[NB];
    const int t = threadIdx.x;
    for (int i = t; i < NB; i += 256) h[i] = 0;
    __syncthreads();
    const int e0 = blockIdx.x * PCHUNK;
    const int e1 = (e0 + PCHUNK < EE) ? e0 + PCHUNK : EE;
    for (int e = e0 + t; e < e1; e += 256)
        atomicAdd(&h[EI[EE + e] >> 8], 1);
    __syncthreads();
    for (int i = t; i < NB; i += 256)
        cur[i] = h[i] ? atomicAdd(&bcursor[i], h[i]) : 0;
    __syncthreads();
    for (int e = e0 + t; e < e1; e += 256) {
        int s = EI[e], d = EI[EE + e];
        int pos = atomicAdd(&cur[d >> 8], 1);
        ebuf[pos] = make_int2(s, d);
    }
}

__global__ __launch_bounds__(256) void k_nhist(const int2* __restrict__ ebuf,
                                               const int* __restrict__ bstart,
                                               int* __restrict__ hist)
{
    __shared__ int cnt[NPB];
    const int b = blockIdx.x, t = threadIdx.x;
    cnt[t] = 0;
    __syncthreads();
    const int e0 = bstart[b], e1 = bstart[b + 1];
    for (int e = e0 + t; e < e1; e += 256)
        atomicAdd(&cnt[ebuf[e].y & (NPB - 1)], 1);
    __syncthreads();
    int idx = b * NPB + t;
    if (idx < NN) hist[idx] = cnt[t];
}

__global__ __launch_bounds__(256) void k_scan1(const int* __restrict__ hist,
                                               int* __restrict__ partials)
{
    __shared__ int red[256];
    int b = blockIdx.x, t = threadIdx.x;
    int i0 = b * SCAN_CHUNK + 2 * t;
    int e0 = (i0 < NN) ? hist[i0] : 0;
    int e1 = (i0 + 1 < NN) ? hist[i0 + 1] : 0;
    red[t] = e0 + e1;
    __syncthreads();
    for (int off = 128; off > 0; off >>= 1) {
        if (t < off) red[t] += red[t + off];
        __syncthreads();
    }
    if (t == 0) partials[b] = red[0];
}

__global__ __launch_bounds__(256) void k_scan2(const int* __restrict__ partials,
                                               int* __restrict__ poffs,
                                               int* __restrict__ row_start)
{
    __shared__ int s[256];
    int t = threadIdx.x;
    int v = (t < SCAN_BLOCKS) ? partials[t] : 0;
    s[t] = v;
    __syncthreads();
    for (int off = 1; off < 256; off <<= 1) {
        int u = (t >= off) ? s[t - off] : 0;
        __syncthreads();
        s[t] += u;
        __syncthreads();
    }
    if (t < SCAN_BLOCKS) poffs[t] = s[t] - v;
    if (t == 0) row_start[NN] = EE;
}

__global__ __launch_bounds__(256) void k_scan3(const int* __restrict__ hist,
                                               const int* __restrict__ poffs,
                                               int* __restrict__ row_start)
{
    __shared__ int s[256];
    int b = blockIdx.x, t = threadIdx.x;
    int i0 = b * SCAN_CHUNK + 2 * t;
    int e0 = (i0 < NN) ? hist[i0] : 0;
    int e1 = (i0 + 1 < NN) ? hist[i0 + 1] : 0;
    int pair = e0 + e1;
    s[t] = pair;
    __syncthreads();
    for (int off = 1; off < 256; off <<= 1) {
        int u = (t >= off) ? s[t - off] : 0;
        __syncthreads();
        s[t] += u;
        __syncthreads();
    }
    int base = poffs[b] + s[t] - pair;
    if (i0 < NN)     row_start[i0] = base;
    if (i0 + 1 < NN) row_start[i0 + 1] = base + e0;
}

__global__ __launch_bounds__(256) void k_fill2(const int2* __restrict__ ebuf,
                                               const int* __restrict__ bstart,
                                               const int* __restrict__ row_start,
                                               int* __restrict__ ssrc)
{
    __shared__ int cur[NPB];
    const int b = blockIdx.x, t = threadIdx.x;
    int idx = b * NPB + t;
    cur[t] = (idx < NN) ? row_start[idx] : 0;
    __syncthreads();
    const int e0 = bstart[b], e1 = bstart[b + 1];
    for (int e = e0 + t; e < e1; e += 256) {
        int2 ed = ebuf[e];
        int pos = atomicAdd(&cur[ed.y & (NPB - 1)], 1);
        ssrc[pos] = ed.x;
    }
}

// ---------------------------------------------------------------------------
// Precision conversions / weight transposes (fp16, [n][k] layout)
// ---------------------------------------------------------------------------

// x (f32, NN*128) -> Xh (fp16), 8 elems/thread
__global__ __launch_bounds__(256) void k_xcast(const float* __restrict__ X,
                                               _Float16* __restrict__ Xh)
{
    int idx = blockIdx.x * 256 + threadIdx.x;   // 1.6M threads
    const float4* src = (const float4*)X;
    float4 a = src[idx * 2], b = src[idx * 2 + 1];
    half8 o = { (_Float16)a.x, (_Float16)a.y, (_Float16)a.z, (_Float16)a.w,
                (_Float16)b.x, (_Float16)b.y, (_Float16)b.z, (_Float16)b.w };
    *(half8*)&Xh[idx * 8] = o;
}

// Wt[n][k] = (fp16) W[k][n]   (W: 128x128 f32 row-major)
__global__ __launch_bounds__(256) void k_wtcast(const float* __restrict__ W,
                                                _Float16* __restrict__ Wt)
{
    int idx = blockIdx.x * 256 + threadIdx.x;   // 16384
    int n = idx >> 7, k = idx & 127;
    Wt[idx] = (_Float16)W[k * 128 + n];
}

// embed weight: Wt[n][k] = (fp16) W1[(200+k)][n]   (W1: 328x128)
__global__ __launch_bounds__(256) void k_wt_embed(const float* __restrict__ W1,
                                                  _Float16* __restrict__ Wt)
{
    int idx = blockIdx.x * 256 + threadIdx.x;
    int n = idx >> 7, k = idx & 127;
    Wt[idx] = (_Float16)W1[(200 + k) * 128 + n];
}

// BN-folded: Wt[n][k] = (fp16)(scale[k] * W1[k][n])
__global__ __launch_bounds__(256) void k_foldWt(const float* __restrict__ W1,
                                                const float* __restrict__ scale,
                                                _Float16* __restrict__ Wt)
{
    int idx = blockIdx.x * 256 + threadIdx.x;
    int n = idx >> 7, k = idx & 127;
    Wt[idx] = (_Float16)(scale[k] * W1[k * 128 + n]);
}

__global__ __launch_bounds__(128) void k_cvec(const float* __restrict__ W1,
                                              const float* __restrict__ shift,
                                              float* __restrict__ cvec)
{
    int j = threadIdx.x;
    float acc = 0.f;
    for (int k = 0; k < 128; ++k) acc = fmaf(shift[k], W1[k * 128 + j], acc);
    cvec[j] = acc;
}

// ---------------------------------------------------------------------------
// fp16 MFMA GEMM core: block = 64 rows x 128 cols, 4 waves in 2x2,
// wave tile = 32 rows x 64 cols. A-frags direct from global (rows beyond n
// read in-bounds garbage from padded buffers; those D rows are discarded).
// Wt (global, [n][k] fp16) staged whole into LDS, rows padded to 136.
// ---------------------------------------------------------------------------

#define MM_PREAMBLE(Wth)                                                     \
    __shared__ _Float16 Wl[128][136];                                        \
    const int tid = threadIdx.x;                                             \
    const int row0 = blockIdx.x * 64;                                        \
    {                                                                        \
        _Float16* wl = &Wl[0][0];                                            \
        for (int it = 0; it < 8; ++it) {                                     \
            int idx = tid + it * 256;                                        \
            int r = idx >> 4, seg = idx & 15;                                \
            *(half8*)&Wl[r][seg * 8] = *(const half8*)&Wth[r * 128 + seg * 8];\
        }                                                                    \
        (void)wl;                                                            \
    }

#define MM_CORE(Ah)                                                          \
    const int lane = tid & 63;                                               \
    const int wv = tid >> 6;                                                 \
    const int ml = lane & 15;                                                \
    const int quad = lane >> 4;                                              \
    const int wr = wv >> 1, wc = wv & 1;                                     \
    floatx4 acc[2][4];                                                       \
    for (int r = 0; r < 2; ++r)                                              \
        for (int t = 0; t < 4; ++t)                                          \
            acc[r][t] = (floatx4){0.f, 0.f, 0.f, 0.f};                       \
    {                                                                        \
        const size_t ar0 = (size_t)(row0 + 32 * wr + ml) * 128;              \
        const size_t ar1 = ar0 + (size_t)16 * 128;                           \
        _Pragma("unroll")                                                    \
        for (int kq = 0; kq < 4; ++kq) {                                     \
            int k0 = kq * 32;                                                \
            half8 a0 = *(const half8*)&Ah[ar0 + k0 + quad * 8];              \
            half8 a1 = *(const half8*)&Ah[ar1 + k0 + quad * 8];              \
            _Pragma("unroll")                                                \
            for (int t = 0; t < 4; ++t) {                                    \
                half8 bf = *(const half8*)&Wl[64 * wc + 16 * t + ml][k0 + quad * 8]; \
                acc[0][t] = __builtin_amdgcn_mfma_f32_16x16x32_f16(a0, bf, acc[0][t], 0, 0, 0); \
                acc[1][t] = __builtin_amdgcn_mfma_f32_16x16x32_f16(a1, bf, acc[1][t], 0, 0, 0); \
            }                                                                \
        }                                                                    \
    }

// P = Xh @ WtE  + W1[z] + W1[100+z]  (f32 row lookups), store fp16
__global__ __launch_bounds__(256) void k_mm_embed(
    const _Float16* __restrict__ Ah, const _Float16* __restrict__ Wth,
    const int* __restrict__ Z, const float* __restrict__ W1,
    _Float16* __restrict__ Ph)
{
    MM_PREAMBLE(Wth)
    __syncthreads();
    MM_CORE(Ah)
    #pragma unroll
    for (int r = 0; r < 2; ++r)
        #pragma unroll
        for (int j = 0; j < 4; ++j) {
            int grow = row0 + 32 * wr + 16 * r + quad * 4 + j;
            if (grow < NN) {
                int zv = Z[grow];
                const float* w0 = &W1[zv * 128];
                const float* w1 = &W1[(100 + zv) * 128];
                #pragma unroll
                for (int t = 0; t < 4; ++t) {
                    int gcol = 64 * wc + 16 * t + ml;
                    float v = acc[r][t][j] + w0[gcol] + w1[gcol];
                    Ph[(size_t)grow * 128 + gcol] = (_Float16)v;
                }
            }
        }
}

// P = A @ Wt (plain store fp16)
__global__ __launch_bounds__(256) void k_mm1(
    const _Float16* __restrict__ Ah, const _Float16* __restrict__ Wth,
    _Float16* __restrict__ Ph)
{
    MM_PREAMBLE(Wth)
    __syncthreads();
    MM_CORE(Ah)
    #pragma unroll
    for (int r = 0; r < 2; ++r)
        #pragma unroll
        for (int j = 0; j < 4; ++j) {
            int grow = row0 + 32 * wr + 16 * r + quad * 4 + j;
            if (grow < NN) {
                #pragma unroll
                for (int t = 0; t < 4; ++t) {
                    int gcol = 64 * wc + 16 * t + ml;
                    Ph[(size_t)grow * 128 + gcol] = (_Float16)acc[r][t][j];
                }
            }
        }
}

// A = relu(M @ Wt2 + b2), store fp16; fused BN stats (f32)
__global__ __launch_bounds__(256) void k_mm2(
    const _Float16* __restrict__ Ah, const _Float16* __restrict__ Wth,
    const float* __restrict__ b2, _Float16* __restrict__ Oh,
    float* __restrict__ colsum, float* __restrict__ colsq)
{
    __shared__ float cs[128];
    __shared__ float cq[128];
    MM_PREAMBLE(Wth)
    if (tid < 128) { cs[tid] = 0.f; cq[tid] = 0.f; }
    __syncthreads();
    MM_CORE(Ah)
    float b2v[4];
    #pragma unroll
    for (int t = 0; t < 4; ++t) b2v[t] = b2[64 * wc + 16 * t + ml];
    float st[4] = {0.f, 0.f, 0.f, 0.f};
    float qt[4] = {0.f, 0.f, 0.f, 0.f};
    #pragma unroll
    for (int r = 0; r < 2; ++r)
        #pragma unroll
        for (int j = 0; j < 4; ++j) {
            int grow = row0 + 32 * wr + 16 * r + quad * 4 + j;
            if (grow < NN) {
                #pragma unroll
                for (int t = 0; t < 4; ++t) {
                    int gcol = 64 * wc + 16 * t + ml;
                    float v = fmaxf(acc[r][t][j] + b2v[t], 0.f);
                    Oh[(size_t)grow * 128 + gcol] = (_Float16)v;
                    st[t] += v;
                    qt[t] += v * v;
                }
            }
        }
    #pragma unroll
    for (int t = 0; t < 4; ++t) {
        int gcol = 64 * wc + 16 * t + ml;
        atomicAdd(&cs[gcol], st[t]);
        atomicAdd(&cq[gcol], qt[t]);
    }
    __syncthreads();
    if (tid < 128) {
        atomicAdd(&colsum[tid], cs[tid]);
        atomicAdd(&colsq[tid], cq[tid]);
    }
}

// ---------------------------------------------------------------------------
// fp16 gather-aggregate: M[i] = relu(P[i] + sum_{j->i} P[j] + b1 + (1+deg)*cvec)
// 32 lanes/node, lane q owns cols [4q,4q+4) (8 B half4 loads)
// ---------------------------------------------------------------------------

__global__ __launch_bounds__(256) void k_aggregate(
    const _Float16* __restrict__ Ph, const int* __restrict__ row_start,
    const int* __restrict__ ssrc, const float* __restrict__ b1,
    const float* __restrict__ cvec, _Float16* __restrict__ Mh)
{
    int idx = blockIdx.x * 256 + threadIdx.x;
    int node = idx >> 5, q = idx & 31;
    if (node >= NN) return;
    int s0 = row_start[node], s1 = row_start[node + 1];
    float degp1 = (float)(s1 - s0 + 1);
    float4 bv = *(const float4*)&b1[q * 4];
    float4 cv = *(const float4*)&cvec[q * 4];
    half4 pv = *(const half4*)&Ph[(size_t)node * 128 + q * 4];
    float ax = (float)pv[0] + fmaf(degp1, cv.x, bv.x);
    float ay = (float)pv[1] + fmaf(degp1, cv.y, bv.y);
    float az = (float)pv[2] + fmaf(degp1, cv.z, bv.z);
    float aw = (float)pv[3] + fmaf(degp1, cv.w, bv.w);
    int e = s0;
    for (; e + 1 < s1; e += 2) {
        int sa = ssrc[e], sb = ssrc[e + 1];
        half4 va = *(const half4*)&Ph[(size_t)sa * 128 + q * 4];
        half4 vb = *(const half4*)&Ph[(size_t)sb * 128 + q * 4];
        ax += (float)va[0] + (float)vb[0];
        ay += (float)va[1] + (float)vb[1];
        az += (float)va[2] + (float)vb[2];
        aw += (float)va[3] + (float)vb[3];
    }
    if (e < s1) {
        int sa = ssrc[e];
        half4 va = *(const half4*)&Ph[(size_t)sa * 128 + q * 4];
        ax += (float)va[0]; ay += (float)va[1];
        az += (float)va[2]; aw += (float)va[3];
    }
    half4 o = { (_Float16)fmaxf(ax, 0.f), (_Float16)fmaxf(ay, 0.f),
                (_Float16)fmaxf(az, 0.f), (_Float16)fmaxf(aw, 0.f) };
    *(half4*)&Mh[(size_t)node * 128 + q * 4] = o;
}

__global__ void k_bnfin(const float* __restrict__ colsum, const float* __restrict__ colsq,
                        const float* __restrict__ g, const float* __restrict__ be,
                        float* __restrict__ scale, float* __restrict__ shift)
{
    int c = threadIdx.x;
    float inv_n = 1.0f / (float)NN;
    float mu = colsum[c] * inv_n;
    float var = colsq[c] * inv_n - mu * mu;
    float sc = g[c] * rsqrtf(var + BN_EPS);
    scale[c] = sc;
    shift[c] = be[c] - mu * sc;
}

// mean-pool per graph with BN applied on the fly (fp16 reads, f32 accumulate)
__global__ __launch_bounds__(128) void k_pool(
    const _Float16* __restrict__ Ah, const int* __restrict__ batch,
    const float* __restrict__ scale, const float* __restrict__ shift,
    float* __restrict__ pooled, int loff)
{
    int g = blockIdx.x;
    int c = threadIdx.x;
    int lo = 0, hi = NN;
    while (lo < hi) { int mid = (lo + hi) >> 1; if (batch[mid] < g) lo = mid + 1; else hi = mid; }
    int s = lo;
    lo = s; hi = NN;
    while (lo < hi) { int mid = (lo + hi) >> 1; if (batch[mid] < g + 1) lo = mid + 1; else hi = mid; }
    int e = lo;
    float acc = 0.f;
    for (int i = s; i < e; ++i) acc += (float)Ah[(size_t)i * 128 + c];
    int cnt = e - s;
    float mean = acc / (float)(cnt > 0 ? cnt : 1);
    pooled[g * 384 + loff + c] = fmaf(scale[c], mean, shift[c]);
}

__global__ __launch_bounds__(128) void k_final(
    const float* __restrict__ pooled,
    const float* __restrict__ Wl1, const float* __restrict__ bl1,
    const float* __restrict__ Wl2, const float* __restrict__ bl2,
    float* __restrict__ out)
{
    __shared__ float pr[384];
    __shared__ float red[128];
    int g = blockIdx.x, j = threadIdx.x;
    for (int i = j; i < 384; i += 128) pr[i] = pooled[g * 384 + i];
    __syncthreads();
    float acc = bl1[j];
    for (int k = 0; k < 384; ++k) acc = fmaf(pr[k], Wl1[k * 128 + j], acc);
    float r = fmaxf(acc, 0.f) * Wl2[j];
    red[j] = r;
    __syncthreads();
    for (int off = 64; off > 0; off >>= 1) {
        if (j < off) red[j] += red[j + off];
        __syncthreads();
    }
    if (j == 0) out[g] = red[0] + bl2[0];
}

extern "C" void kernel_launch(void* const* d_in, const int* in_sizes, int n_in,
                              void* d_out, int out_size, void* d_ws, size_t ws_size,
                              hipStream_t stream)
{
    const float* x     = (const float*)d_in[0];
    const int*   z     = (const int*)d_in[1];
    const int*   ei    = (const int*)d_in[2];
    const int*   batch = (const int*)d_in[3];
    const float* W1a[3] = {(const float*)d_in[4],  (const float*)d_in[10], (const float*)d_in[16]};
    const float* b1a[3] = {(const float*)d_in[5],  (const float*)d_in[11], (const float*)d_in[17]};
    const float* W2a[3] = {(const float*)d_in[6],  (const float*)d_in[12], (const float*)d_in[18]};
    const float* b2a[3] = {(const float*)d_in[7],  (const float*)d_in[13], (const float*)d_in[19]};
    const float* ga[3]  = {(const float*)d_in[8],  (const float*)d_in[14], (const float*)d_in[20]};
    const float* bea[3] = {(const float*)d_in[9],  (const float*)d_in[15], (const float*)d_in[21]};
    const float* Wl1 = (const float*)d_in[22];
    const float* bl1 = (const float*)d_in[23];
    const float* Wl2 = (const float*)d_in[24];
    const float* bl2 = (const float*)d_in[25];
    float* out = (float*)d_out;

    char* ws = (char*)d_ws;
    size_t off = 0;
    auto alloc = [&](size_t bytes) {
        void* p = ws + off;
        off += (bytes + 255) & ~(size_t)255;
        return p;
    };
    _Float16* Xh  = (_Float16*)alloc((size_t)NROWS_PAD * 128 * 2);
    _Float16* Ph  = (_Float16*)alloc((size_t)NROWS_PAD * 128 * 2);
    _Float16* Mh  = (_Float16*)alloc((size_t)NROWS_PAD * 128 * 2);
    _Float16* Ahb = (_Float16*)alloc((size_t)NROWS_PAD * 128 * 2);
    _Float16* WtE = (_Float16*)alloc((size_t)128 * 128 * 2);
    _Float16* Wt1 = (_Float16*)alloc((size_t)128 * 128 * 2);
    _Float16* Wt2 = (_Float16*)alloc((size_t)128 * 128 * 2);
    int2*  ebuf     = (int2*)alloc((size_t)EE * 8);
    int*   ssrc     = (int*)alloc((size_t)EE * 4);
    int*   hist     = (int*)alloc((size_t)NN * 4);
    int*   row_st   = (int*)alloc((size_t)(NN + 1) * 4);
    int*   bcount   = (int*)alloc((size_t)NB * 4);
    int*   bstart   = (int*)alloc((size_t)(NB + 1) * 4);
    int*   bcursor  = (int*)alloc((size_t)NB * 4);
    int*   partials = (int*)alloc((size_t)SCAN_BLOCKS * 4);
    int*   poffs    = (int*)alloc((size_t)SCAN_BLOCKS * 4);
    float* cvec     = (float*)alloc(128 * 4);
    float* cvec0    = (float*)alloc(128 * 4);
    float* colsum   = (float*)alloc(128 * 4);
    float* colsq    = (float*)alloc(128 * 4);
    float* scale    = (float*)alloc(128 * 4);
    float* shift    = (float*)alloc(128 * 4);
    float* pooled   = (float*)alloc((size_t)GG * 384 * 4);

    const int gemmBlocks = (NN + 63) / 64;           // 1563
    const int aggBlocks  = (NN * 32 + 255) / 256;

    // ---- one-time per call: casts + CSR build ----
    hipMemsetAsync(bcount, 0, (size_t)NB * 4, stream);
    hipMemsetAsync(cvec0, 0, 128 * 4, stream);
    k_xcast<<<(NN * 128 / 8 + 255) / 256, 256, 0, stream>>>(x, Xh);
    k_wt_embed<<<64, 256, 0, stream>>>(W1a[0], WtE);
    k_bhist<<<PBLOCKS, 256, 0, stream>>>(ei, bcount);
    k_bscan<<<1, 512, 0, stream>>>(bcount, bstart, bcursor);
    k_part<<<PBLOCKS, 256, 0, stream>>>(ei, bcursor, ebuf);
    k_nhist<<<NB, 256, 0, stream>>>(ebuf, bstart, hist);
    k_scan1<<<SCAN_BLOCKS, 256, 0, stream>>>(hist, partials);
    k_scan2<<<1, 256, 0, stream>>>(partials, poffs, row_st);
    k_scan3<<<SCAN_BLOCKS, 256, 0, stream>>>(hist, poffs, row_st);
    k_fill2<<<NB, 256, 0, stream>>>(ebuf, bstart, row_st, ssrc);

    for (int l = 0; l < 3; ++l) {
        hipMemsetAsync(colsum, 0, 128 * 4, stream);
        hipMemsetAsync(colsq, 0, 128 * 4, stream);
        const float* cv = cvec0;
        if (l == 0) {
            k_mm_embed<<<gemmBlocks, 256, 0, stream>>>(Xh, WtE, z, W1a[0], Ph);
        } else {
            k_foldWt<<<64, 256, 0, stream>>>(W1a[l], scale, Wt1);
            k_cvec<<<1, 128, 0, stream>>>(W1a[l], shift, cvec);
            k_mm1<<<gemmBlocks, 256, 0, stream>>>(Ahb, Wt1, Ph);
            cv = cvec;
        }
        k_wtcast<<<64, 256, 0, stream>>>(W2a[l], Wt2);
        k_aggregate<<<aggBlocks, 256, 0, stream>>>(Ph, row_st, ssrc, b1a[l], cv, Mh);
        k_mm2<<<gemmBlocks, 256, 0, stream>>>(Mh, Wt2, b2a[l], Ahb, colsum, colsq);
        k_bnfin<<<1, 128, 0, stream>>>(colsum, colsq, ga[l], bea[l], scale, shift);
        k_pool<<<GG, 128, 0, stream>>>(Ahb, batch, scale, shift, pooled, l * 128);
    }
    k_final<<<GG, 128, 0, stream>>>(pooled, Wl1, bl1, Wl2, bl2, out);
}

// Round 6
// 713.515 us; speedup vs baseline: 12.3668x; 1.2979x over previous
//
#include <hip/hip_runtime.h>
#include <hip/hip_bf16.h>

#define NN 100000
#define NROWS_PAD 100032
#define EE 1600000
#define GG 512
#define SCAN_CHUNK 512
#define SCAN_BLOCKS ((NN + SCAN_CHUNK - 1) / SCAN_CHUNK)   // 196
#define NPB 256                                            // nodes per bucket
#define NB  ((NN + NPB - 1) / NPB)                         // 391 buckets
#define PCHUNK 4096                                        // edges per partition block
#define PBLOCKS ((EE + PCHUNK - 1) / PCHUNK)               // 391
static constexpr float BN_EPS = 1e-5f;

typedef _Float16 half8 __attribute__((ext_vector_type(8)));
typedef _Float16 half4 __attribute__((ext_vector_type(4)));
typedef float floatx4 __attribute__((ext_vector_type(4)));

// ---------------------------------------------------------------------------
// CSR build (write-local). ebuf entries packed: src (bits 0-16) | dst&255 << 17
// ---------------------------------------------------------------------------

__global__ __launch_bounds__(256) void k_bhist(const int* __restrict__ EI,
                                               int* __restrict__ bcount)
{
    __shared__ int h[NB];
    const int t = threadIdx.x;
    for (int i = t; i < NB; i += 256) h[i] = 0;
    __syncthreads();
    const int e0 = blockIdx.x * PCHUNK;
    const int e1 = (e0 + PCHUNK < EE) ? e0 + PCHUNK : EE;
    for (int e = e0 + t; e < e1; e += 256)
        atomicAdd(&h[EI[EE + e] >> 8], 1);
    __syncthreads();
    for (int i = t; i < NB; i += 256)
        if (h[i]) atomicAdd(&bcount[i], h[i]);
}

__global__ __launch_bounds__(512) void k_bscan(const int* __restrict__ bcount,
                                               int* __restrict__ bstart,
                                               int* __restrict__ bcursor)
{
    __shared__ int s[512];
    int t = threadIdx.x;
    int v = (t < NB) ? bcount[t] : 0;
    s[t] = v;
    __syncthreads();
    for (int off = 1; off < 512; off <<= 1) {
        int u = (t >= off) ? s[t - off] : 0;
        __syncthreads();
        s[t] += u;
        __syncthreads();
    }
    if (t < NB) { int ex = s[t] - v; bstart[t] = ex; bcursor[t] = ex; }
    if (t == 0) bstart[NB] = EE;
}

__global__ __launch_bounds__(256) void k_part(const int* __restrict__ EI,
                                              int* __restrict__ bcursor,
                                              int* __restrict__ ebuf)
{
    __shared__ int h[NB];
    __shared__ int cur[NB];
    const int t = threadIdx.x;
    for (int i = t; i < NB; i += 256) h[i] = 0;
    __syncthreads();
    const int e0 = blockIdx.x * PCHUNK;
    const int e1 = (e0 + PCHUNK < EE) ? e0 + PCHUNK : EE;
    for (int e = e0 + t; e < e1; e += 256)
        atomicAdd(&h[EI[EE + e] >> 8], 1);
    __syncthreads();
    for (int i = t; i < NB; i += 256)
        cur[i] = h[i] ? atomicAdd(&bcursor[i], h[i]) : 0;
    __syncthreads();
    for (int e = e0 + t; e < e1; e += 256) {
        int s = EI[e], d = EI[EE + e];
        int pos = atomicAdd(&cur[d >> 8], 1);
        ebuf[pos] = s | ((d & (NPB - 1)) << 17);
    }
}

__global__ __launch_bounds__(256) void k_nhist(const int* __restrict__ ebuf,
                                               const int* __restrict__ bstart,
                                               int* __restrict__ hist)
{
    __shared__ int cnt[NPB];
    const int b = blockIdx.x, t = threadIdx.x;
    cnt[t] = 0;
    __syncthreads();
    const int e0 = bstart[b], e1 = bstart[b + 1];
    for (int e = e0 + t; e < e1; e += 256) {
        unsigned p = (unsigned)__builtin_nontemporal_load(&ebuf[e]);
        atomicAdd(&cnt[p >> 17], 1);
    }
    __syncthreads();
    int idx = b * NPB + t;
    if (idx < NN) hist[idx] = cnt[t];
}

__global__ __launch_bounds__(256) void k_scan1(const int* __restrict__ hist,
                                               int* __restrict__ partials)
{
    __shared__ int red[256];
    int b = blockIdx.x, t = threadIdx.x;
    int i0 = b * SCAN_CHUNK + 2 * t;
    int e0 = (i0 < NN) ? hist[i0] : 0;
    int e1 = (i0 + 1 < NN) ? hist[i0 + 1] : 0;
    red[t] = e0 + e1;
    __syncthreads();
    for (int off = 128; off > 0; off >>= 1) {
        if (t < off) red[t] += red[t + off];
        __syncthreads();
    }
    if (t == 0) partials[b] = red[0];
}

__global__ __launch_bounds__(256) void k_scan2(const int* __restrict__ partials,
                                               int* __restrict__ poffs,
                                               int* __restrict__ row_start)
{
    __shared__ int s[256];
    int t = threadIdx.x;
    int v = (t < SCAN_BLOCKS) ? partials[t] : 0;
    s[t] = v;
    __syncthreads();
    for (int off = 1; off < 256; off <<= 1) {
        int u = (t >= off) ? s[t - off] : 0;
        __syncthreads();
        s[t] += u;
        __syncthreads();
    }
    if (t < SCAN_BLOCKS) poffs[t] = s[t] - v;
    if (t == 0) row_start[NN] = EE;
}

__global__ __launch_bounds__(256) void k_scan3(const int* __restrict__ hist,
                                               const int* __restrict__ poffs,
                                               int* __restrict__ row_start)
{
    __shared__ int s[256];
    int b = blockIdx.x, t = threadIdx.x;
    int i0 = b * SCAN_CHUNK + 2 * t;
    int e0 = (i0 < NN) ? hist[i0] : 0;
    int e1 = (i0 + 1 < NN) ? hist[i0 + 1] : 0;
    int pair = e0 + e1;
    s[t] = pair;
    __syncthreads();
    for (int off = 1; off < 256; off <<= 1) {
        int u = (t >= off) ? s[t - off] : 0;
        __syncthreads();
        s[t] += u;
        __syncthreads();
    }
    int base = poffs[b] + s[t] - pair;
    if (i0 < NN)     row_start[i0] = base;
    if (i0 + 1 < NN) row_start[i0 + 1] = base + e0;
}

__global__ __launch_bounds__(256) void k_fill2(const int* __restrict__ ebuf,
                                               const int* __restrict__ bstart,
                                               const int* __restrict__ row_start,
                                               int* __restrict__ ssrc)
{
    __shared__ int cur[NPB];
    const int b = blockIdx.x, t = threadIdx.x;
    int idx = b * NPB + t;
    cur[t] = (idx < NN) ? row_start[idx] : 0;
    __syncthreads();
    const int e0 = bstart[b], e1 = bstart[b + 1];
    for (int e = e0 + t; e < e1; e += 256) {
        unsigned p = (unsigned)__builtin_nontemporal_load(&ebuf[e]);
        int pos = atomicAdd(&cur[p >> 17], 1);
        ssrc[pos] = (int)(p & 0x1FFFFu);
    }
}

// ---------------------------------------------------------------------------
// x cast (once) + per-layer weight prep (fused)
// ---------------------------------------------------------------------------

__global__ __launch_bounds__(256) void k_xcast(const float* __restrict__ X,
                                               _Float16* __restrict__ Xh)
{
    int idx = blockIdx.x * 256 + threadIdx.x;
    const float4* src = (const float4*)X;
    float4 a = src[idx * 2], b = src[idx * 2 + 1];
    half8 o = { (_Float16)a.x, (_Float16)a.y, (_Float16)a.z, (_Float16)a.w,
                (_Float16)b.x, (_Float16)b.y, (_Float16)b.z, (_Float16)b.w };
    *(half8*)&Xh[idx * 8] = o;
}

// blocks 0-63: Wt1 ([n][k], BN-folded or embed slice)
// blocks 64-127: Wt2 ([n][k] cast)
// block 128: cvec (zeros for l==0)
__global__ __launch_bounds__(256) void k_prep(
    const float* __restrict__ W1, const float* __restrict__ W2,
    const float* __restrict__ scale, const float* __restrict__ shift,
    _Float16* __restrict__ Wt1, _Float16* __restrict__ Wt2,
    float* __restrict__ cvec, int l)
{
    int b = blockIdx.x, t = threadIdx.x;
    if (b < 64) {
        int idx = b * 256 + t;
        int n = idx >> 7, k = idx & 127;
        Wt1[idx] = (l == 0) ? (_Float16)W1[(200 + k) * 128 + n]
                            : (_Float16)(scale[k] * W1[k * 128 + n]);
    } else if (b < 128) {
        int idx = (b - 64) * 256 + t;
        int n = idx >> 7, k = idx & 127;
        Wt2[idx] = (_Float16)W2[k * 128 + n];
    } else if (t < 128) {
        float acc = 0.f;
        if (l != 0)
            for (int k = 0; k < 128; ++k) acc = fmaf(shift[k], W1[k * 128 + t], acc);
        cvec[t] = acc;
    }
}

// ---------------------------------------------------------------------------
// fp16 MFMA GEMM core (as R5): block 64x128, 4 waves 2x2, wave tile 32x64
// ---------------------------------------------------------------------------

#define MM_PREAMBLE(Wth)                                                     \
    __shared__ _Float16 Wl[128][136];                                        \
    const int tid = threadIdx.x;                                             \
    const int row0 = blockIdx.x * 64;                                        \
    {                                                                        \
        for (int it = 0; it < 8; ++it) {                                     \
            int idx = tid + it * 256;                                        \
            int r = idx >> 4, seg = idx & 15;                                \
            *(half8*)&Wl[r][seg * 8] = *(const half8*)&Wth[r * 128 + seg * 8];\
        }                                                                    \
    }

#define MM_CORE(Ah)                                                          \
    const int lane = tid & 63;                                               \
    const int wv = tid >> 6;                                                 \
    const int ml = lane & 15;                                                \
    const int quad = lane >> 4;                                              \
    const int wr = wv >> 1, wc = wv & 1;                                     \
    floatx4 acc[2][4];                                                       \
    for (int r = 0; r < 2; ++r)                                              \
        for (int t = 0; t < 4; ++t)                                          \
            acc[r][t] = (floatx4){0.f, 0.f, 0.f, 0.f};                       \
    {                                                                        \
        const size_t ar0 = (size_t)(row0 + 32 * wr + ml) * 128;              \
        const size_t ar1 = ar0 + (size_t)16 * 128;                           \
        _Pragma("unroll")                                                    \
        for (int kq = 0; kq < 4; ++kq) {                                     \
            int k0 = kq * 32;                                                \
            half8 a0 = *(const half8*)&Ah[ar0 + k0 + quad * 8];              \
            half8 a1 = *(const half8*)&Ah[ar1 + k0 + quad * 8];              \
            _Pragma("unroll")                                                \
            for (int t = 0; t < 4; ++t) {                                    \
                half8 bf = *(const half8*)&Wl[64 * wc + 16 * t + ml][k0 + quad * 8]; \
                acc[0][t] = __builtin_amdgcn_mfma_f32_16x16x32_f16(a0, bf, acc[0][t], 0, 0, 0); \
                acc[1][t] = __builtin_amdgcn_mfma_f32_16x16x32_f16(a1, bf, acc[1][t], 0, 0, 0); \
            }                                                                \
        }                                                                    \
    }

__global__ __launch_bounds__(256) void k_mm_embed(
    const _Float16* __restrict__ Ah, const _Float16* __restrict__ Wth,
    const int* __restrict__ Z, const float* __restrict__ W1,
    _Float16* __restrict__ Ph)
{
    MM_PREAMBLE(Wth)
    __syncthreads();
    MM_CORE(Ah)
    #pragma unroll
    for (int r = 0; r < 2; ++r)
        #pragma unroll
        for (int j = 0; j < 4; ++j) {
            int grow = row0 + 32 * wr + 16 * r + quad * 4 + j;
            if (grow < NN) {
                int zv = Z[grow];
                const float* w0 = &W1[zv * 128];
                const float* w1 = &W1[(100 + zv) * 128];
                #pragma unroll
                for (int t = 0; t < 4; ++t) {
                    int gcol = 64 * wc + 16 * t + ml;
                    float v = acc[r][t][j] + w0[gcol] + w1[gcol];
                    Ph[(size_t)grow * 128 + gcol] = (_Float16)v;
                }
            }
        }
}

__global__ __launch_bounds__(256) void k_mm1(
    const _Float16* __restrict__ Ah, const _Float16* __restrict__ Wth,
    _Float16* __restrict__ Ph)
{
    MM_PREAMBLE(Wth)
    __syncthreads();
    MM_CORE(Ah)
    #pragma unroll
    for (int r = 0; r < 2; ++r)
        #pragma unroll
        for (int j = 0; j < 4; ++j) {
            int grow = row0 + 32 * wr + 16 * r + quad * 4 + j;
            if (grow < NN) {
                #pragma unroll
                for (int t = 0; t < 4; ++t) {
                    int gcol = 64 * wc + 16 * t + ml;
                    Ph[(size_t)grow * 128 + gcol] = (_Float16)acc[r][t][j];
                }
            }
        }
}

__global__ __launch_bounds__(256) void k_mm2(
    const _Float16* __restrict__ Ah, const _Float16* __restrict__ Wth,
    const float* __restrict__ b2, _Float16* __restrict__ Oh,
    float* __restrict__ colsum, float* __restrict__ colsq)
{
    __shared__ float cs[128];
    __shared__ float cq[128];
    MM_PREAMBLE(Wth)
    if (tid < 128) { cs[tid] = 0.f; cq[tid] = 0.f; }
    __syncthreads();
    MM_CORE(Ah)
    float b2v[4];
    #pragma unroll
    for (int t = 0; t < 4; ++t) b2v[t] = b2[64 * wc + 16 * t + ml];
    float st[4] = {0.f, 0.f, 0.f, 0.f};
    float qt[4] = {0.f, 0.f, 0.f, 0.f};
    #pragma unroll
    for (int r = 0; r < 2; ++r)
        #pragma unroll
        for (int j = 0; j < 4; ++j) {
            int grow = row0 + 32 * wr + 16 * r + quad * 4 + j;
            if (grow < NN) {
                #pragma unroll
                for (int t = 0; t < 4; ++t) {
                    int gcol = 64 * wc + 16 * t + ml;
                    float v = fmaxf(acc[r][t][j] + b2v[t], 0.f);
                    Oh[(size_t)grow * 128 + gcol] = (_Float16)v;
                    st[t] += v;
                    qt[t] += v * v;
                }
            }
        }
    #pragma unroll
    for (int t = 0; t < 4; ++t) {
        int gcol = 64 * wc + 16 * t + ml;
        atomicAdd(&cs[gcol], st[t]);
        atomicAdd(&cq[gcol], qt[t]);
    }
    __syncthreads();
    if (tid < 128) {
        atomicAdd(&colsum[tid], cs[tid]);
        atomicAdd(&colsq[tid], cq[tid]);
    }
}

// ---------------------------------------------------------------------------
// gather-aggregate: 16 lanes/node, half8 loads, 4-edge unroll
// ---------------------------------------------------------------------------

__global__ __launch_bounds__(256) void k_aggregate(
    const _Float16* __restrict__ Ph, const int* __restrict__ row_start,
    const int* __restrict__ ssrc, const float* __restrict__ b1,
    const float* __restrict__ cvec, _Float16* __restrict__ Mh)
{
    int idx = blockIdx.x * 256 + threadIdx.x;
    int node = idx >> 4, q = idx & 15;
    if (node >= NN) return;
    int s0 = row_start[node], s1 = row_start[node + 1];
    float degp1 = (float)(s1 - s0 + 1);
    float acc[8];
    half8 pv = *(const half8*)&Ph[(size_t)node * 128 + q * 8];
    #pragma unroll
    for (int j = 0; j < 8; ++j)
        acc[j] = (float)pv[j] + fmaf(degp1, cvec[q * 8 + j], b1[q * 8 + j]);
    int e = s0;
    for (; e + 3 < s1; e += 4) {
        int sa = __builtin_nontemporal_load(&ssrc[e]);
        int sb = __builtin_nontemporal_load(&ssrc[e + 1]);
        int sc = __builtin_nontemporal_load(&ssrc[e + 2]);
        int sd = __builtin_nontemporal_load(&ssrc[e + 3]);
        half8 va = *(const half8*)&Ph[(size_t)sa * 128 + q * 8];
        half8 vb = *(const half8*)&Ph[(size_t)sb * 128 + q * 8];
        half8 vc = *(const half8*)&Ph[(size_t)sc * 128 + q * 8];
        half8 vd = *(const half8*)&Ph[(size_t)sd * 128 + q * 8];
        #pragma unroll
        for (int j = 0; j < 8; ++j)
            acc[j] += ((float)va[j] + (float)vb[j]) + ((float)vc[j] + (float)vd[j]);
    }
    for (; e < s1; ++e) {
        int sa = __builtin_nontemporal_load(&ssrc[e]);
        half8 va = *(const half8*)&Ph[(size_t)sa * 128 + q * 8];
        #pragma unroll
        for (int j = 0; j < 8; ++j) acc[j] += (float)va[j];
    }
    half8 o;
    #pragma unroll
    for (int j = 0; j < 8; ++j) o[j] = (_Float16)fmaxf(acc[j], 0.f);
    __builtin_nontemporal_store(o, (half8*)&Mh[(size_t)node * 128 + q * 8]);
}

__global__ void k_bnfin(const float* __restrict__ colsum, const float* __restrict__ colsq,
                        const float* __restrict__ g, const float* __restrict__ be,
                        float* __restrict__ scale, float* __restrict__ shift)
{
    int c = threadIdx.x;
    float inv_n = 1.0f / (float)NN;
    float mu = colsum[c] * inv_n;
    float var = colsq[c] * inv_n - mu * mu;
    float sc = g[c] * rsqrtf(var + BN_EPS);
    scale[c] = sc;
    shift[c] = be[c] - mu * sc;
}

// mean-pool per graph, BN applied on the fly; 8 row-groups x 16 col-segs
__global__ __launch_bounds__(128) void k_pool(
    const _Float16* __restrict__ Ah, const int* __restrict__ batch,
    const float* __restrict__ scale, const float* __restrict__ shift,
    float* __restrict__ pooled, int loff)
{
    __shared__ float red[8][128];
    int g = blockIdx.x;
    int t = threadIdx.x;
    int rg = t >> 4, seg = t & 15;
    int lo = 0, hi = NN;
    while (lo < hi) { int mid = (lo + hi) >> 1; if (batch[mid] < g) lo = mid + 1; else hi = mid; }
    int s = lo;
    lo = s; hi = NN;
    while (lo < hi) { int mid = (lo + hi) >> 1; if (batch[mid] < g + 1) lo = mid + 1; else hi = mid; }
    int e = lo;
    float acc[8] = {};
    for (int i = s + rg; i < e; i += 8) {
        half8 v = *(const half8*)&Ah[(size_t)i * 128 + seg * 8];
        #pragma unroll
        for (int j = 0; j < 8; ++j) acc[j] += (float)v[j];
    }
    #pragma unroll
    for (int j = 0; j < 8; ++j) red[rg][seg * 8 + j] = acc[j];
    __syncthreads();
    int cnt = e - s;
    float inv = 1.0f / (float)(cnt > 0 ? cnt : 1);
    if (t < 128) {
        float s_ = 0.f;
        #pragma unroll
        for (int r = 0; r < 8; ++r) s_ += red[r][t];
        pooled[g * 384 + loff + t] = fmaf(scale[t], s_ * inv, shift[t]);
    }
}

__global__ __launch_bounds__(128) void k_final(
    const float* __restrict__ pooled,
    const float* __restrict__ Wl1, const float* __restrict__ bl1,
    const float* __restrict__ Wl2, const float* __restrict__ bl2,
    float* __restrict__ out)
{
    __shared__ float pr[384];
    __shared__ float red[128];
    int g = blockIdx.x, j = threadIdx.x;
    for (int i = j; i < 384; i += 128) pr[i] = pooled[g * 384 + i];
    __syncthreads();
    float acc = bl1[j];
    for (int k = 0; k < 384; ++k) acc = fmaf(pr[k], Wl1[k * 128 + j], acc);
    float r = fmaxf(acc, 0.f) * Wl2[j];
    red[j] = r;
    __syncthreads();
    for (int off = 64; off > 0; off >>= 1) {
        if (j < off) red[j] += red[j + off];
        __syncthreads();
    }
    if (j == 0) out[g] = red[0] + bl2[0];
}

extern "C" void kernel_launch(void* const* d_in, const int* in_sizes, int n_in,
                              void* d_out, int out_size, void* d_ws, size_t ws_size,
                              hipStream_t stream)
{
    const float* x     = (const float*)d_in[0];
    const int*   z     = (const int*)d_in[1];
    const int*   ei    = (const int*)d_in[2];
    const int*   batch = (const int*)d_in[3];
    const float* W1a[3] = {(const float*)d_in[4],  (const float*)d_in[10], (const float*)d_in[16]};
    const float* b1a[3] = {(const float*)d_in[5],  (const float*)d_in[11], (const float*)d_in[17]};
    const float* W2a[3] = {(const float*)d_in[6],  (const float*)d_in[12], (const float*)d_in[18]};
    const float* b2a[3] = {(const float*)d_in[7],  (const float*)d_in[13], (const float*)d_in[19]};
    const float* ga[3]  = {(const float*)d_in[8],  (const float*)d_in[14], (const float*)d_in[20]};
    const float* bea[3] = {(const float*)d_in[9],  (const float*)d_in[15], (const float*)d_in[21]};
    const float* Wl1 = (const float*)d_in[22];
    const float* bl1 = (const float*)d_in[23];
    const float* Wl2 = (const float*)d_in[24];
    const float* bl2 = (const float*)d_in[25];
    float* out = (float*)d_out;

    char* ws = (char*)d_ws;
    size_t off = 0;
    auto alloc = [&](size_t bytes) {
        void* p = ws + off;
        off += (bytes + 255) & ~(size_t)255;
        return p;
    };
    _Float16* Xh  = (_Float16*)alloc((size_t)NROWS_PAD * 128 * 2);
    _Float16* Ph  = (_Float16*)alloc((size_t)NROWS_PAD * 128 * 2);
    _Float16* Mh  = (_Float16*)alloc((size_t)NROWS_PAD * 128 * 2);
    _Float16* Ahb = (_Float16*)alloc((size_t)NROWS_PAD * 128 * 2);
    _Float16* Wt1 = (_Float16*)alloc((size_t)128 * 128 * 2);
    _Float16* Wt2 = (_Float16*)alloc((size_t)128 * 128 * 2);
    int*   ebuf     = (int*)alloc((size_t)EE * 4);
    int*   ssrc     = (int*)alloc((size_t)EE * 4);
    int*   hist     = (int*)alloc((size_t)NN * 4);
    int*   row_st   = (int*)alloc((size_t)(NN + 1) * 4);
    int*   bcount   = (int*)alloc((size_t)NB * 4);
    int*   bstart   = (int*)alloc((size_t)(NB + 1) * 4);
    int*   bcursor  = (int*)alloc((size_t)NB * 4);
    int*   partials = (int*)alloc((size_t)SCAN_BLOCKS * 4);
    int*   poffs    = (int*)alloc((size_t)SCAN_BLOCKS * 4);
    float* cvec     = (float*)alloc(128 * 4);
    float* stats    = (float*)alloc(3 * 256 * 4);   // per-layer colsum|colsq
    float* scale    = (float*)alloc(128 * 4);
    float* shift    = (float*)alloc(128 * 4);
    float* pooled   = (float*)alloc((size_t)GG * 384 * 4);

    const int gemmBlocks = (NN + 63) / 64;           // 1563
    const int aggBlocks  = (NN * 16 + 255) / 256;    // 6250

    // ---- one-time per call: zero stats, cast x, CSR build ----
    hipMemsetAsync(stats, 0, 3 * 256 * 4, stream);
    hipMemsetAsync(bcount, 0, (size_t)NB * 4, stream);
    k_xcast<<<(NN * 128 / 8 + 255) / 256, 256, 0, stream>>>(x, Xh);
    k_bhist<<<PBLOCKS, 256, 0, stream>>>(ei, bcount);
    k_bscan<<<1, 512, 0, stream>>>(bcount, bstart, bcursor);
    k_part<<<PBLOCKS, 256, 0, stream>>>(ei, bcursor, ebuf);
    k_nhist<<<NB, 256, 0, stream>>>(ebuf, bstart, hist);
    k_scan1<<<SCAN_BLOCKS, 256, 0, stream>>>(hist, partials);
    k_scan2<<<1, 256, 0, stream>>>(partials, poffs, row_st);
    k_scan3<<<SCAN_BLOCKS, 256, 0, stream>>>(hist, poffs, row_st);
    k_fill2<<<NB, 256, 0, stream>>>(ebuf, bstart, row_st, ssrc);

    for (int l = 0; l < 3; ++l) {
        float* colsum = stats + l * 256;
        float* colsq  = stats + l * 256 + 128;
        k_prep<<<129, 256, 0, stream>>>(W1a[l], W2a[l], scale, shift, Wt1, Wt2, cvec, l);
        if (l == 0)
            k_mm_embed<<<gemmBlocks, 256, 0, stream>>>(Xh, Wt1, z, W1a[0], Ph);
        else
            k_mm1<<<gemmBlocks, 256, 0, stream>>>(Ahb, Wt1, Ph);
        k_aggregate<<<aggBlocks, 256, 0, stream>>>(Ph, row_st, ssrc, b1a[l], cvec, Mh);
        k_mm2<<<gemmBlocks, 256, 0, stream>>>(Mh, Wt2, b2a[l], Ahb, colsum, colsq);
        k_bnfin<<<1, 128, 0, stream>>>(colsum, colsq, ga[l], bea[l], scale, shift);
        k_pool<<<GG, 128, 0, stream>>>(Ahb, batch, scale, shift, pooled, l * 128);
    }
    k_final<<<GG, 128, 0, stream>>>(pooled, Wl1, bl1, Wl2, bl2, out);
}